// Round 11
// baseline (153.232 us; speedup 1.0000x reference)
//
#include <hip/hip_runtime.h>
#include <math.h>

// ---------------------------------------------------------------------------
// SpatialProximityHead on MI355X — round 10: 7 dispatches via row-slab fusion.
// pack -> fcqkv(L0) -> attn(L0) -> oprojqkv(L0->L1) -> attn(L1)
//      -> oprojmlpU -> pair
// GEMM chains fused per 16-row slab, activations passed via LDS bf16 panels.
// ---------------------------------------------------------------------------

#define NTOK 512
#define HDIM 256
#define DKH  64
#define NHEAD 4
#define TLEN 6
#define WSZ  65536
#define PSTR 520   // attn P_lds ushort stride
#define XPS  264   // LDS panel ushort stride (16 rows x 256 cols)

typedef __attribute__((ext_vector_type(8))) short bf16x8;
typedef __attribute__((ext_vector_type(4))) float f32x4;

__device__ __forceinline__ ushort f2bf(float f)
{
    unsigned u = __builtin_bit_cast(unsigned, f);
    u += 0x7FFFu + ((u >> 16) & 1u);     // RNE
    return (ushort)(u >> 16);
}

struct PKArg {
    const float* w[13];
    const float* pl;
    ushort* wpk;
    float *dist, *dwraw, *inv_cs;
};

// ---------------------------------------------------------------------------
// pack: 0-207 weight 64x64 transpose tiles ([col][k] bf16); 208-215 dist prep.
// ---------------------------------------------------------------------------
__global__ __launch_bounds__(256) void pack_kernel(PKArg p)
{
    __shared__ __align__(16) ushort smu[64 * 72];
    const int bid = blockIdx.x;
    const int t   = threadIdx.x;

    if (bid < 208) {
        const int mat  = bid >> 4;
        const int tile = bid & 15;
        const int k0   = (tile >> 2) * 64;
        const int c0   = (tile & 3) * 64;
        const float* W = p.w[mat];
#pragma unroll
        for (int j = 0; j < 4; ++j) {
            const int i  = t + j * 256;
            const int r  = i >> 4, c4 = i & 15;
            const float4 v4 = *(const float4*)&W[(k0 + r) * HDIM + c0 + c4 * 4];
            smu[(c4 * 4 + 0) * 72 + r] = f2bf(v4.x);
            smu[(c4 * 4 + 1) * 72 + r] = f2bf(v4.y);
            smu[(c4 * 4 + 2) * 72 + r] = f2bf(v4.z);
            smu[(c4 * 4 + 3) * 72 + r] = f2bf(v4.w);
        }
        __syncthreads();
#pragma unroll
        for (int j = 0; j < 2; ++j) {
            const int i  = t + j * 256;
            const int cr = i >> 3, kk = i & 7;
            const uint4 v = *(const uint4*)&smu[cr * 72 + kk * 8];
            *(uint4*)&p.wpk[mat * WSZ + (c0 + cr) * HDIM + k0 + kk * 8] = v;
        }
    } else {
        float* smf = (float*)smu;
        float* qe  = smf;            // [512][3]
        float* red = smf + 1536;     // [4][64]
        const int item = bid - 208;
        for (int i = t; i < 512; i += 256) {
            qe[i * 3 + 0] = p.pl[i * 33 + 30];
            qe[i * 3 + 1] = p.pl[i * 33 + 31];
            qe[i * 3 + 2] = p.pl[i * 33 + 32];
        }
        __syncthreads();
        const int m   = item * 64 + (t & 63);
        const int nch = t >> 6;
        const float kx = p.pl[m * 33 + 0], ky = p.pl[m * 33 + 1], kz = p.pl[m * 33 + 2];
        float cs = 0.f;
        for (int n = nch * 128; n < nch * 128 + 128; ++n) {
            const float dx = kx - qe[n * 3 + 0];
            const float dy = ky - qe[n * 3 + 1];
            const float dz = kz - qe[n * 3 + 2];
            const float dd = sqrtf(dx * dx + dy * dy + dz * dz);
            const float w  = 1.0f / (dd + 0.01f);
            p.dist[n * NTOK + m]  = dd;
            p.dwraw[n * NTOK + m] = w;
            cs += w;
        }
        red[nch * 64 + (t & 63)] = cs;
        __syncthreads();
        if (t < 64)
            p.inv_cs[item * 64 + t] =
                1.0f / (red[t] + red[64 + t] + red[128 + t] + red[192 + t]);
    }
}

// ---------------------------------------------------------------------------
// qkv phase (shared): per wave 16 rows x 64 cols x 3 problems, A from LDS
// panel, B from packed weights. Writes q16/k16 row-major, v transposed.
// ---------------------------------------------------------------------------
__device__ __forceinline__ void qkv_phase(
    const ushort* __restrict__ xpan,
    const ushort* __restrict__ WqT, const float* __restrict__ bq,
    const ushort* __restrict__ WkT, const float* __restrict__ bk,
    const ushort* __restrict__ WvT, const float* __restrict__ bv,
    int slab, int c0, int lr, int lg, int lk,
    ushort* __restrict__ q16, ushort* __restrict__ k16,
    ushort* __restrict__ vT16)
{
    const ushort* Ap = xpan + lr * XPS + lk;
#pragma unroll
    for (int p = 0; p < 3; ++p) {
        const ushort* Wt = (p == 0) ? WqT : (p == 1) ? WkT : WvT;
        const float*  bb = (p == 0) ? bq  : (p == 1) ? bk  : bv;
        f32x4 acc[4];
#pragma unroll
        for (int j = 0; j < 4; ++j) acc[j] = (f32x4){0.f, 0.f, 0.f, 0.f};
#pragma unroll
        for (int ks = 0; ks < 8; ++ks) {
            const bf16x8 a = *(const bf16x8*)&Ap[ks * 32];
#pragma unroll
            for (int j = 0; j < 4; ++j) {
                const bf16x8 b = *(const bf16x8*)&Wt[(c0 + j * 16 + lr) * HDIM + ks * 32 + lk];
                acc[j] = __builtin_amdgcn_mfma_f32_16x16x32_bf16(a, b, acc[j], 0, 0, 0);
            }
        }
#pragma unroll
        for (int j = 0; j < 4; ++j) {
            const int col = c0 + j * 16 + lr;
            const float bv2 = bb[col];
            if (p < 2) {
                ushort* dst = (p == 0) ? q16 : k16;
#pragma unroll
                for (int rg = 0; rg < 4; ++rg)
                    dst[(slab + lg * 4 + rg) * HDIM + col] = f2bf(acc[j][rg] + bv2);
            } else {
                ushort4 s = {f2bf(acc[j][0] + bv2), f2bf(acc[j][1] + bv2),
                             f2bf(acc[j][2] + bv2), f2bf(acc[j][3] + bv2)};
                *(ushort4*)&vT16[col * NTOK + slab + lg * 4] = s;
            }
        }
    }
}

// ---------------------------------------------------------------------------
// fcqkv: slab = 16 rows. Phase 1: x = relu(qf@fcW+fcb) (A converted from f32
// in-frag) -> x f32 global + LDS panel. Phase 2: q/k/v (L0). 32 blocks.
// ---------------------------------------------------------------------------
__global__ __launch_bounds__(256) void fcqkv(
    const float* __restrict__ qf, const ushort* __restrict__ fcWt,
    const float* __restrict__ fcb,
    const ushort* __restrict__ WqT, const float* __restrict__ bq,
    const ushort* __restrict__ WkT, const float* __restrict__ bk,
    const ushort* __restrict__ WvT, const float* __restrict__ bv,
    float* __restrict__ x, ushort* __restrict__ q16,
    ushort* __restrict__ k16, ushort* __restrict__ vT16)
{
    __shared__ __align__(16) ushort xpan[16 * XPS];
    const int slab = blockIdx.x * 16;
    const int t = threadIdx.x;
    const int wv = t >> 6, lane = t & 63;
    const int lr = lane & 15, lg = lane >> 4, lk = lg * 8;
    const int c0 = wv * 64;

    {   // phase 1: fc
        f32x4 acc[4];
#pragma unroll
        for (int j = 0; j < 4; ++j) acc[j] = (f32x4){0.f, 0.f, 0.f, 0.f};
        const float* Aq = qf + (slab + lr) * HDIM + lk;
#pragma unroll
        for (int ks = 0; ks < 8; ++ks) {
            const float4 a0 = *(const float4*)&Aq[ks * 32];
            const float4 a1 = *(const float4*)&Aq[ks * 32 + 4];
            bf16x8 a;
            a[0] = (short)f2bf(a0.x); a[1] = (short)f2bf(a0.y);
            a[2] = (short)f2bf(a0.z); a[3] = (short)f2bf(a0.w);
            a[4] = (short)f2bf(a1.x); a[5] = (short)f2bf(a1.y);
            a[6] = (short)f2bf(a1.z); a[7] = (short)f2bf(a1.w);
#pragma unroll
            for (int j = 0; j < 4; ++j) {
                const bf16x8 b = *(const bf16x8*)&fcWt[(c0 + j * 16 + lr) * HDIM + ks * 32 + lk];
                acc[j] = __builtin_amdgcn_mfma_f32_16x16x32_bf16(a, b, acc[j], 0, 0, 0);
            }
        }
#pragma unroll
        for (int j = 0; j < 4; ++j) {
            const int col = c0 + j * 16 + lr;
            const float bbv = fcb[col];
#pragma unroll
            for (int rg = 0; rg < 4; ++rg) {
                const float o = fmaxf(acc[j][rg] + bbv, 0.f);
                x[(slab + lg * 4 + rg) * HDIM + col] = o;
                xpan[(lg * 4 + rg) * XPS + col] = f2bf(o);
            }
        }
    }
    __syncthreads();
    qkv_phase(xpan, WqT, bq, WkT, bk, WvT, bv, slab, c0, lr, lg, lk,
              q16, k16, vT16);
}

// ---------------------------------------------------------------------------
// attn_fused: unchanged from round 9/10 (proven). 128 blocks x 256 thr.
// ---------------------------------------------------------------------------
__global__ __launch_bounds__(256) void attn_fused(
    const ushort* __restrict__ q16, const ushort* __restrict__ k16,
    const ushort* __restrict__ vT16, const float* __restrict__ dist,
    const float* __restrict__ dwraw, const float* __restrict__ inv_cs,
    ushort* __restrict__ ao16)
{
    __shared__ __align__(16) ushort P_lds[16 * PSTR];
    __shared__ __align__(16) float exch[4][16][64];
    __shared__ float rmax[4][16];
    __shared__ float psums[4][16];

    const int bid = blockIdx.x;
    const int h  = bid >> 5;
    const int n0 = (bid & 31) * 16;
    const int t  = threadIdx.x;
    const int wv = t >> 6, lane = t & 63;
    const int lr = lane & 15, lg = lane >> 4, lk = lg * 8;
    const int mW = wv * 128;

    const ushort* Qrow = q16 + (n0 + lr) * HDIM + h * DKH + lk;
    const bf16x8 a0 = *(const bf16x8*)&Qrow[0];
    const bf16x8 a1 = *(const bf16x8*)&Qrow[32];

    f32x4 accs[8];
#pragma unroll
    for (int cg = 0; cg < 8; ++cg) accs[cg] = (f32x4){0.f, 0.f, 0.f, 0.f};
#pragma unroll
    for (int cg = 0; cg < 8; ++cg) {
        const ushort* Brow = k16 + (mW + cg * 16 + lr) * HDIM + h * DKH + lk;
        accs[cg] = __builtin_amdgcn_mfma_f32_16x16x32_bf16(
            a0, *(const bf16x8*)&Brow[0], accs[cg], 0, 0, 0);
        accs[cg] = __builtin_amdgcn_mfma_f32_16x16x32_bf16(
            a1, *(const bf16x8*)&Brow[32], accs[cg], 0, 0, 0);
    }

    float s[8][4];
#pragma unroll
    for (int cg = 0; cg < 8; ++cg) {
        const int m = mW + cg * 16 + lr;
        const float ic = (h == 0) ? inv_cs[m] : 0.f;
#pragma unroll
        for (int rg = 0; rg < 4; ++rg) {
            const int n = n0 + lg * 4 + rg;
            float b = 0.f;
            if (h == 0)      b = dwraw[n * NTOK + m] * ic;
            else if (h == 1) b = -dist[n * NTOK + m];
            s[cg][rg] = accs[cg][rg] * 0.125f + b;
        }
    }

    float mx[4];
#pragma unroll
    for (int rg = 0; rg < 4; ++rg) {
        float m = s[0][rg];
#pragma unroll
        for (int cg = 1; cg < 8; ++cg) m = fmaxf(m, s[cg][rg]);
#pragma unroll
        for (int o = 1; o < 16; o <<= 1) m = fmaxf(m, __shfl_xor(m, o));
        mx[rg] = m;
    }
    if (lr == 0)
#pragma unroll
        for (int rg = 0; rg < 4; ++rg) rmax[wv][lg * 4 + rg] = mx[rg];
    __syncthreads();
    float mxf[4];
#pragma unroll
    for (int rg = 0; rg < 4; ++rg) {
        const int row = lg * 4 + rg;
        mxf[rg] = fmaxf(fmaxf(rmax[0][row], rmax[1][row]),
                        fmaxf(rmax[2][row], rmax[3][row]));
    }

    float ps[4] = {0.f, 0.f, 0.f, 0.f};
#pragma unroll
    for (int cg = 0; cg < 8; ++cg)
#pragma unroll
        for (int rg = 0; rg < 4; ++rg) {
            const float e = __expf(s[cg][rg] - mxf[rg]);
            ps[rg] += e;
            P_lds[(lg * 4 + rg) * PSTR + mW + cg * 16 + lr] = f2bf(e);
        }
#pragma unroll
    for (int rg = 0; rg < 4; ++rg) {
#pragma unroll
        for (int o = 1; o < 16; o <<= 1) ps[rg] += __shfl_xor(ps[rg], o);
    }
    if (lr == 0)
#pragma unroll
        for (int rg = 0; rg < 4; ++rg) psums[wv][lg * 4 + rg] = ps[rg];
    __syncthreads();

    f32x4 acco[4];
#pragma unroll
    for (int db = 0; db < 4; ++db) acco[db] = (f32x4){0.f, 0.f, 0.f, 0.f};
#pragma unroll
    for (int c = 0; c < 4; ++c) {
        const bf16x8 pa = *(const bf16x8*)&P_lds[lr * PSTR + mW + c * 32 + lk];
#pragma unroll
        for (int db = 0; db < 4; ++db) {
            const bf16x8 b = *(const bf16x8*)
                &vT16[(h * DKH + db * 16 + lr) * NTOK + mW + c * 32 + lk];
            acco[db] = __builtin_amdgcn_mfma_f32_16x16x32_bf16(pa, b, acco[db], 0, 0, 0);
        }
    }
#pragma unroll
    for (int db = 0; db < 4; ++db)
#pragma unroll
        for (int rg = 0; rg < 4; ++rg)
            exch[wv][lg * 4 + rg][db * 16 + lr] = acco[db][rg];
    __syncthreads();

    {
        const int r = t >> 4, d4 = t & 15;
        f32x4 sum = *(const f32x4*)&exch[0][r][d4 * 4];
        sum += *(const f32x4*)&exch[1][r][d4 * 4];
        sum += *(const f32x4*)&exch[2][r][d4 * 4];
        sum += *(const f32x4*)&exch[3][r][d4 * 4];
        const float inv = 1.0f / (psums[0][r] + psums[1][r] + psums[2][r] + psums[3][r]);
        ushort4 o = {f2bf(sum.x * inv), f2bf(sum.y * inv),
                     f2bf(sum.z * inv), f2bf(sum.w * inv)};
        *(ushort4*)&ao16[(n0 + r) * HDIM + h * DKH + d4 * 4] = o;
    }
}

// ---------------------------------------------------------------------------
// oproj+LN phase (shared): y = ao16@WoT + bo + x_in; LN -> result into acc.
// Returns normalized values in acc; caller writes outputs.
// ---------------------------------------------------------------------------
__device__ __forceinline__ void oprojln_phase(
    const ushort* __restrict__ ao16, const ushort* __restrict__ WoT,
    const float* __restrict__ bo, const float* __restrict__ gamma,
    const float* __restrict__ beta, const float* __restrict__ x,
    int slab, int c0, int wv, int lr, int lg, int lk,
    float red[4][16], f32x4 acc[4])
{
    const ushort* Arow = ao16 + (slab + lr) * HDIM + lk;
#pragma unroll
    for (int j = 0; j < 4; ++j) acc[j] = (f32x4){0.f, 0.f, 0.f, 0.f};
#pragma unroll
    for (int ks = 0; ks < 8; ++ks) {
        const bf16x8 a = *(const bf16x8*)&Arow[ks * 32];
#pragma unroll
        for (int j = 0; j < 4; ++j) {
            const bf16x8 b = *(const bf16x8*)&WoT[(c0 + j * 16 + lr) * HDIM + ks * 32 + lk];
            acc[j] = __builtin_amdgcn_mfma_f32_16x16x32_bf16(a, b, acc[j], 0, 0, 0);
        }
    }
#pragma unroll
    for (int j = 0; j < 4; ++j) {
        const int col = c0 + j * 16 + lr;
        const float bc = bo[col];
#pragma unroll
        for (int rg = 0; rg < 4; ++rg)
            acc[j][rg] += bc + x[(slab + lg * 4 + rg) * HDIM + col];
    }

    float sm[4];
#pragma unroll
    for (int rg = 0; rg < 4; ++rg) {
        float s = 0.f;
#pragma unroll
        for (int j = 0; j < 4; ++j) s += acc[j][rg];
#pragma unroll
        for (int o = 1; o < 16; o <<= 1) s += __shfl_xor(s, o);
        sm[rg] = s;
    }
    if (lr == 0)
#pragma unroll
        for (int rg = 0; rg < 4; ++rg) red[wv][lg * 4 + rg] = sm[rg];
    __syncthreads();
    float mean[4];
#pragma unroll
    for (int rg = 0; rg < 4; ++rg) {
        const int row = lg * 4 + rg;
        mean[rg] = (red[0][row] + red[1][row] + red[2][row] + red[3][row]) * (1.f / 256.f);
    }
    __syncthreads();

#pragma unroll
    for (int rg = 0; rg < 4; ++rg) {
        float s2 = 0.f;
#pragma unroll
        for (int j = 0; j < 4; ++j) {
            const float c = acc[j][rg] - mean[rg];
            s2 += c * c;
        }
#pragma unroll
        for (int o = 1; o < 16; o <<= 1) s2 += __shfl_xor(s2, o);
        sm[rg] = s2;
    }
    if (lr == 0)
#pragma unroll
        for (int rg = 0; rg < 4; ++rg) red[wv][lg * 4 + rg] = sm[rg];
    __syncthreads();
    float rstd[4];
#pragma unroll
    for (int rg = 0; rg < 4; ++rg) {
        const int row = lg * 4 + rg;
        const float var = (red[0][row] + red[1][row] + red[2][row] + red[3][row]) * (1.f / 256.f);
        rstd[rg] = rsqrtf(var + 1e-5f);
    }
#pragma unroll
    for (int j = 0; j < 4; ++j) {
        const int col = c0 + j * 16 + lr;
        const float gg = gamma[col], bv = beta[col];
#pragma unroll
        for (int rg = 0; rg < 4; ++rg)
            acc[j][rg] = (acc[j][rg] - mean[rg]) * rstd[rg] * gg + bv;
    }
}

// ---------------------------------------------------------------------------
// oprojqkv: oproj+resid+LN (layer L) -> x f32 + LDS panel -> qkv (layer L+1).
// 32 blocks x 256 thr.
// ---------------------------------------------------------------------------
__global__ __launch_bounds__(256) void oprojqkv(
    const ushort* __restrict__ ao16, const ushort* __restrict__ WoT,
    const float* __restrict__ bo, const float* __restrict__ gamma,
    const float* __restrict__ beta,
    const ushort* __restrict__ WqT, const float* __restrict__ bq,
    const ushort* __restrict__ WkT, const float* __restrict__ bk,
    const ushort* __restrict__ WvT, const float* __restrict__ bv,
    float* __restrict__ x, ushort* __restrict__ q16,
    ushort* __restrict__ k16, ushort* __restrict__ vT16)
{
    __shared__ __align__(16) ushort xpan[16 * XPS];
    __shared__ float red[4][16];
    const int slab = blockIdx.x * 16;
    const int t = threadIdx.x;
    const int wv = t >> 6, lane = t & 63;
    const int lr = lane & 15, lg = lane >> 4, lk = lg * 8;
    const int c0 = wv * 64;

    f32x4 acc[4];
    oprojln_phase(ao16, WoT, bo, gamma, beta, x, slab, c0, wv, lr, lg, lk, red, acc);
#pragma unroll
    for (int j = 0; j < 4; ++j) {
        const int col = c0 + j * 16 + lr;
#pragma unroll
        for (int rg = 0; rg < 4; ++rg) {
            x[(slab + lg * 4 + rg) * HDIM + col] = acc[j][rg];
            xpan[(lg * 4 + rg) * XPS + col] = f2bf(acc[j][rg]);
        }
    }
    __syncthreads();
    qkv_phase(xpan, WqT, bq, WkT, bk, WvT, bv, slab, c0, lr, lg, lk,
              q16, k16, vT16);
}

// ---------------------------------------------------------------------------
// oprojmlpU: oproj+resid+LN (L1) -> panel -> mlp o1/o2 panels -> U1/U2 f32.
// 32 blocks x 256 thr.
// ---------------------------------------------------------------------------
__global__ __launch_bounds__(256) void oprojmlpU(
    const ushort* __restrict__ ao16, const ushort* __restrict__ WoT,
    const float* __restrict__ bo, const float* __restrict__ gamma,
    const float* __restrict__ beta,
    const ushort* __restrict__ m1WT, const float* __restrict__ m1b,
    const ushort* __restrict__ m2WT, const float* __restrict__ m2b,
    const ushort* __restrict__ cW1aT, const float* __restrict__ cb1,
    const ushort* __restrict__ cW1bT,
    const float* __restrict__ x, float* __restrict__ U1, float* __restrict__ U2)
{
    __shared__ __align__(16) ushort xpan[16 * XPS];
    __shared__ __align__(16) ushort o1pan[16 * XPS];
    __shared__ __align__(16) ushort o2pan[16 * XPS];
    __shared__ float red[4][16];
    const int slab = blockIdx.x * 16;
    const int t = threadIdx.x;
    const int wv = t >> 6, lane = t & 63;
    const int lr = lane & 15, lg = lane >> 4, lk = lg * 8;
    const int c0 = wv * 64;

    f32x4 acc[4];
    oprojln_phase(ao16, WoT, bo, gamma, beta, x, slab, c0, wv, lr, lg, lk, red, acc);
#pragma unroll
    for (int j = 0; j < 4; ++j) {
        const int col = c0 + j * 16 + lr;
#pragma unroll
        for (int rg = 0; rg < 4; ++rg)
            xpan[(lg * 4 + rg) * XPS + col] = f2bf(acc[j][rg]);
    }
    __syncthreads();

    // mlp: o1 = relu(x@m1+b1), o2 = relu(x@m2+b2)
    const ushort* Ap = xpan + lr * XPS + lk;
#pragma unroll
    for (int p = 0; p < 2; ++p) {
        const ushort* Wt = p ? m2WT : m1WT;
        const float*  bb = p ? m2b  : m1b;
        ushort* opan     = p ? o2pan : o1pan;
        f32x4 a2[4];
#pragma unroll
        for (int j = 0; j < 4; ++j) a2[j] = (f32x4){0.f, 0.f, 0.f, 0.f};
#pragma unroll
        for (int ks = 0; ks < 8; ++ks) {
            const bf16x8 a = *(const bf16x8*)&Ap[ks * 32];
#pragma unroll
            for (int j = 0; j < 4; ++j) {
                const bf16x8 b = *(const bf16x8*)&Wt[(c0 + j * 16 + lr) * HDIM + ks * 32 + lk];
                a2[j] = __builtin_amdgcn_mfma_f32_16x16x32_bf16(a, b, a2[j], 0, 0, 0);
            }
        }
#pragma unroll
        for (int j = 0; j < 4; ++j) {
            const int col = c0 + j * 16 + lr;
            const float bbv = bb[col];
#pragma unroll
            for (int rg = 0; rg < 4; ++rg)
                opan[(lg * 4 + rg) * XPS + col] = f2bf(fmaxf(a2[j][rg] + bbv, 0.f));
        }
    }
    __syncthreads();

    // U: U1 = o1@cW1a + cb1, U2 = o2@cW1b
#pragma unroll
    for (int p = 0; p < 2; ++p) {
        const ushort* opan = p ? o2pan : o1pan;
        const ushort* Wt   = p ? cW1bT : cW1aT;
        float* U           = p ? U2 : U1;
        const ushort* Ao = opan + lr * XPS + lk;
        f32x4 a2[4];
#pragma unroll
        for (int j = 0; j < 4; ++j) a2[j] = (f32x4){0.f, 0.f, 0.f, 0.f};
#pragma unroll
        for (int ks = 0; ks < 8; ++ks) {
            const bf16x8 a = *(const bf16x8*)&Ao[ks * 32];
#pragma unroll
            for (int j = 0; j < 4; ++j) {
                const bf16x8 b = *(const bf16x8*)&Wt[(c0 + j * 16 + lr) * HDIM + ks * 32 + lk];
                a2[j] = __builtin_amdgcn_mfma_f32_16x16x32_bf16(a, b, a2[j], 0, 0, 0);
            }
        }
#pragma unroll
        for (int j = 0; j < 4; ++j) {
            const int col = c0 + j * 16 + lr;
            const float bbv = (p == 0) ? cb1[col] : 0.f;
#pragma unroll
            for (int rg = 0; rg < 4; ++rg)
                U[(slab + lg * 4 + rg) * HDIM + col] = a2[j][rg] + bbv;
        }
    }
}

// ---------------------------------------------------------------------------
// pair_cls: 32x32 tile, 2x2 per thread, TL copies. (f32 inputs, proven)
// ---------------------------------------------------------------------------
__global__ __launch_bounds__(256) void pair_cls(const float* __restrict__ U1,
                                                const float* __restrict__ U2,
                                                const float* __restrict__ W2,
                                                const float* __restrict__ b2,
                                                float* __restrict__ out)
{
    __shared__ __align__(16) float u1s[32][260];
    __shared__ __align__(16) float u2s[32][260];
    __shared__ __align__(16) float w2s[256];
    const int t  = threadIdx.x;
    const int n0 = blockIdx.y * 32, m0 = blockIdx.x * 32;

    for (int i = t; i < 32 * 64; i += 256) {
        const int r = i >> 6, c4 = i & 63;
        *(float4*)&u1s[r][c4 * 4] = *(const float4*)&U1[(n0 + r) * HDIM + c4 * 4];
        *(float4*)&u2s[r][c4 * 4] = *(const float4*)&U2[(m0 + r) * HDIM + c4 * 4];
    }
    if (t < 64) *(float4*)&w2s[t * 4] = *(const float4*)&W2[t * 4];
    __syncthreads();

    const int tx = t & 15, ty = t >> 4;
    float acc[2][2] = {};
    for (int h4 = 0; h4 < 64; ++h4) {
        const float4 a0 = *(const float4*)&u1s[ty * 2][h4 * 4];
        const float4 a1 = *(const float4*)&u1s[ty * 2 + 1][h4 * 4];
        const float4 b0 = *(const float4*)&u2s[tx * 2][h4 * 4];
        const float4 b1 = *(const float4*)&u2s[tx * 2 + 1][h4 * 4];
        const float4 w  = *(const float4*)&w2s[h4 * 4];
#define RT(A, B) fmaxf((A) + (B), 0.f)
        acc[0][0] += RT(a0.x,b0.x)*w.x + RT(a0.y,b0.y)*w.y + RT(a0.z,b0.z)*w.z + RT(a0.w,b0.w)*w.w;
        acc[0][1] += RT(a0.x,b1.x)*w.x + RT(a0.y,b1.y)*w.y + RT(a0.z,b1.z)*w.z + RT(a0.w,b1.w)*w.w;
        acc[1][0] += RT(a1.x,b0.x)*w.x + RT(a1.y,b0.y)*w.y + RT(a1.z,b0.z)*w.z + RT(a1.w,b0.w)*w.w;
        acc[1][1] += RT(a1.x,b1.x)*w.x + RT(a1.y,b1.y)*w.y + RT(a1.z,b1.z)*w.z + RT(a1.w,b1.w)*w.w;
#undef RT
    }
    const float bbv = b2[0];
#pragma unroll
    for (int ii = 0; ii < 2; ++ii)
#pragma unroll
        for (int jj = 0; jj < 2; ++jj) {
            const float val = acc[ii][jj] + bbv;
            const int n = n0 + ty * 2 + ii;
            const int m = m0 + tx * 2 + jj;
#pragma unroll
            for (int tl = 0; tl < TLEN; ++tl)
                out[tl * NTOK * NTOK + n * NTOK + m] = val;
        }
}

// ---------------------------------------------------------------------------
extern "C" void kernel_launch(void* const* d_in, const int* in_sizes, int n_in,
                              void* d_out, int out_size, void* d_ws, size_t ws_size,
                              hipStream_t stream)
{
    const float* hs   = (const float*)d_in[0];
    const float* qf   = hs + 5 * NTOK * HDIM;
    const float* alp  = (const float*)d_in[1];
    const float* pl   = alp + 5 * NTOK * 33;
    const float* fc_W = (const float*)d_in[2];
    const float* fc_b = (const float*)d_in[3];
    const float* Wq   = (const float*)d_in[4];
    const float* bq   = (const float*)d_in[5];
    const float* Wk   = (const float*)d_in[6];
    const float* bk   = (const float*)d_in[7];
    const float* Wv   = (const float*)d_in[8];
    const float* bv   = (const float*)d_in[9];
    const float* Wo   = (const float*)d_in[10];
    const float* bo   = (const float*)d_in[11];
    const float* lng  = (const float*)d_in[12];
    const float* lnb  = (const float*)d_in[13];
    const float* m1W  = (const float*)d_in[14];
    const float* m1b  = (const float*)d_in[15];
    const float* m2W  = (const float*)d_in[16];
    const float* m2b  = (const float*)d_in[17];
    const float* cW1  = (const float*)d_in[18];
    const float* cb1  = (const float*)d_in[19];
    const float* cW2  = (const float*)d_in[20];
    const float* cb2  = (const float*)d_in[21];
    float* out = (float*)d_out;

    const int NN  = NTOK * NTOK;
    const int NH_ = NTOK * HDIM;
    float* ws     = (float*)d_ws;
    float* dist   = ws;                       // NN
    float* dwraw  = ws + NN;                  // NN
    float* inv_cs = ws + 2 * NN;              // 512
    float* x      = ws + 2 * NN + 512;        // NH
    float* U1     = x + NH_;                  // NH
    float* U2     = U1 + NH_;                 // NH
    ushort* u16   = (ushort*)(U2 + NH_);
    ushort* wpk   = u16;                      // 13 * WSZ
    ushort* q16   = wpk + 13 * WSZ;           // NH
    ushort* k16   = q16 + NH_;                // NH
    ushort* vT16  = k16 + NH_;                // NH ([d][m])
    ushort* ao16  = vT16 + NH_;               // NH

    PKArg pk;
    pk.w[0]  = fc_W;
    pk.w[1]  = Wq;  pk.w[2]  = Wq + WSZ;
    pk.w[3]  = Wk;  pk.w[4]  = Wk + WSZ;
    pk.w[5]  = Wv;  pk.w[6]  = Wv + WSZ;
    pk.w[7]  = Wo;  pk.w[8]  = Wo + WSZ;
    pk.w[9]  = m1W; pk.w[10] = m2W;
    pk.w[11] = cW1; pk.w[12] = cW1 + WSZ;
    pk.pl = pl;
    pk.wpk = wpk;
    pk.dist = dist; pk.dwraw = dwraw; pk.inv_cs = inv_cs;
    pack_kernel<<<216, 256, 0, stream>>>(pk);

    // fc + qkv (L0)
    fcqkv<<<32, 256, 0, stream>>>(
        qf, wpk + 0 * WSZ, fc_b,
        wpk + 1 * WSZ, bq, wpk + 3 * WSZ, bk, wpk + 5 * WSZ, bv,
        x, q16, k16, vT16);

    attn_fused<<<128, 256, 0, stream>>>(q16, k16, vT16, dist, dwraw, inv_cs, ao16);

    // oproj+LN (L0) -> qkv (L1)
    oprojqkv<<<32, 256, 0, stream>>>(
        ao16, wpk + 7 * WSZ, bo, lng, lnb,
        wpk + 2 * WSZ, bq + HDIM, wpk + 4 * WSZ, bk + HDIM,
        wpk + 6 * WSZ, bv + HDIM,
        x, q16, k16, vT16);

    attn_fused<<<128, 256, 0, stream>>>(q16, k16, vT16, dist, dwraw, inv_cs, ao16);

    // oproj+LN (L1) -> mlp -> U
    oprojmlpU<<<32, 256, 0, stream>>>(
        ao16, wpk + 8 * WSZ, bo + HDIM, lng + HDIM, lnb + HDIM,
        wpk + 9 * WSZ, m1b, wpk + 10 * WSZ, m2b,
        wpk + 11 * WSZ, cb1, wpk + 12 * WSZ,
        x, U1, U2);

    pair_cls<<<dim3(16, 16), 256, 0, stream>>>(U1, U2, cW2, cb2, out);
}

// Round 12
// 110.882 us; speedup vs baseline: 1.3819x; 1.3819x over previous
//
#include <hip/hip_runtime.h>
#include <math.h>

// ---------------------------------------------------------------------------
// SpatialProximityHead on MI355X — round 11: 7 dispatches, replicated-width
// slab fusion. Block = (16-row slab, problem replica p): phase-1 (fc or
// oproj+LN) replicated across p, phase-2 computes problem p only.
// pack(216) -> fcqkv(96) -> attn(128) -> oprojqkv(96) -> attn(128)
//           -> oprojmlpU(64) -> pair(256)
// ---------------------------------------------------------------------------

#define NTOK 512
#define HDIM 256
#define DKH  64
#define NHEAD 4
#define TLEN 6
#define WSZ  65536
#define PSTR 520   // attn P_lds ushort stride
#define XPS  264   // LDS panel ushort stride (16 rows x 256 cols)

typedef __attribute__((ext_vector_type(8))) short bf16x8;
typedef __attribute__((ext_vector_type(4))) float f32x4;

__device__ __forceinline__ ushort f2bf(float f)
{
    unsigned u = __builtin_bit_cast(unsigned, f);
    u += 0x7FFFu + ((u >> 16) & 1u);     // RNE
    return (ushort)(u >> 16);
}

struct PKArg {
    const float* w[13];
    const float* pl;
    ushort* wpk;
    float *dist, *dwraw, *inv_cs;
};

// ---------------------------------------------------------------------------
// pack: 0-207 weight 64x64 transpose tiles ([col][k] bf16); 208-215 dist prep.
// ---------------------------------------------------------------------------
__global__ __launch_bounds__(256) void pack_kernel(PKArg p)
{
    __shared__ __align__(16) ushort smu[64 * 72];
    const int bid = blockIdx.x;
    const int t   = threadIdx.x;

    if (bid < 208) {
        const int mat  = bid >> 4;
        const int tile = bid & 15;
        const int k0   = (tile >> 2) * 64;
        const int c0   = (tile & 3) * 64;
        const float* W = p.w[mat];
#pragma unroll
        for (int j = 0; j < 4; ++j) {
            const int i  = t + j * 256;
            const int r  = i >> 4, c4 = i & 15;
            const float4 v4 = *(const float4*)&W[(k0 + r) * HDIM + c0 + c4 * 4];
            smu[(c4 * 4 + 0) * 72 + r] = f2bf(v4.x);
            smu[(c4 * 4 + 1) * 72 + r] = f2bf(v4.y);
            smu[(c4 * 4 + 2) * 72 + r] = f2bf(v4.z);
            smu[(c4 * 4 + 3) * 72 + r] = f2bf(v4.w);
        }
        __syncthreads();
#pragma unroll
        for (int j = 0; j < 2; ++j) {
            const int i  = t + j * 256;
            const int cr = i >> 3, kk = i & 7;
            const uint4 v = *(const uint4*)&smu[cr * 72 + kk * 8];
            *(uint4*)&p.wpk[mat * WSZ + (c0 + cr) * HDIM + k0 + kk * 8] = v;
        }
    } else {
        float* smf = (float*)smu;
        float* qe  = smf;            // [512][3]
        float* red = smf + 1536;     // [4][64]
        const int item = bid - 208;
        for (int i = t; i < 512; i += 256) {
            qe[i * 3 + 0] = p.pl[i * 33 + 30];
            qe[i * 3 + 1] = p.pl[i * 33 + 31];
            qe[i * 3 + 2] = p.pl[i * 33 + 32];
        }
        __syncthreads();
        const int m   = item * 64 + (t & 63);
        const int nch = t >> 6;
        const float kx = p.pl[m * 33 + 0], ky = p.pl[m * 33 + 1], kz = p.pl[m * 33 + 2];
        float cs = 0.f;
        for (int n = nch * 128; n < nch * 128 + 128; ++n) {
            const float dx = kx - qe[n * 3 + 0];
            const float dy = ky - qe[n * 3 + 1];
            const float dz = kz - qe[n * 3 + 2];
            const float dd = sqrtf(dx * dx + dy * dy + dz * dz);
            const float w  = 1.0f / (dd + 0.01f);
            p.dist[n * NTOK + m]  = dd;
            p.dwraw[n * NTOK + m] = w;
            cs += w;
        }
        red[nch * 64 + (t & 63)] = cs;
        __syncthreads();
        if (t < 64)
            p.inv_cs[item * 64 + t] =
                1.0f / (red[t] + red[64 + t] + red[128 + t] + red[192 + t]);
    }
}

// ---------------------------------------------------------------------------
// qkv_one: one qkv problem p for this slab. A from LDS panel, B from packed
// weights. p==0 -> q16 row-major, p==1 -> k16 row-major, p==2 -> vT16.
// ---------------------------------------------------------------------------
__device__ __forceinline__ void qkv_one(
    const ushort* __restrict__ xpan, const ushort* __restrict__ Wt,
    const float* __restrict__ bb, int p,
    int slab, int c0, int lr, int lg, int lk,
    ushort* __restrict__ q16, ushort* __restrict__ k16,
    ushort* __restrict__ vT16)
{
    const ushort* Ap = xpan + lr * XPS + lk;
    f32x4 acc[4];
#pragma unroll
    for (int j = 0; j < 4; ++j) acc[j] = (f32x4){0.f, 0.f, 0.f, 0.f};
#pragma unroll
    for (int ks = 0; ks < 8; ++ks) {
        const bf16x8 a = *(const bf16x8*)&Ap[ks * 32];
#pragma unroll
        for (int j = 0; j < 4; ++j) {
            const bf16x8 b = *(const bf16x8*)&Wt[(c0 + j * 16 + lr) * HDIM + ks * 32 + lk];
            acc[j] = __builtin_amdgcn_mfma_f32_16x16x32_bf16(a, b, acc[j], 0, 0, 0);
        }
    }
#pragma unroll
    for (int j = 0; j < 4; ++j) {
        const int col = c0 + j * 16 + lr;
        const float bv2 = bb[col];
        if (p < 2) {
            ushort* dst = (p == 0) ? q16 : k16;
#pragma unroll
            for (int rg = 0; rg < 4; ++rg)
                dst[(slab + lg * 4 + rg) * HDIM + col] = f2bf(acc[j][rg] + bv2);
        } else {
            ushort4 s = {f2bf(acc[j][0] + bv2), f2bf(acc[j][1] + bv2),
                         f2bf(acc[j][2] + bv2), f2bf(acc[j][3] + bv2)};
            *(ushort4*)&vT16[col * NTOK + slab + lg * 4] = s;
        }
    }
}

// ---------------------------------------------------------------------------
// fcqkv: 96 blocks. p = bid>>5 (replica), slab = (bid&31)*16.
// Phase 1 (all replicas): x = relu(qf@fcW+fcb) -> xpan (+ x f32 if p==0).
// Phase 2: qkv problem p.
// ---------------------------------------------------------------------------
__global__ __launch_bounds__(256) void fcqkv(
    const float* __restrict__ qf, const ushort* __restrict__ fcWt,
    const float* __restrict__ fcb,
    const ushort* __restrict__ WqT, const float* __restrict__ bq,
    const ushort* __restrict__ WkT, const float* __restrict__ bk,
    const ushort* __restrict__ WvT, const float* __restrict__ bv,
    float* __restrict__ x, ushort* __restrict__ q16,
    ushort* __restrict__ k16, ushort* __restrict__ vT16)
{
    __shared__ __align__(16) ushort xpan[16 * XPS];
    const int bid  = blockIdx.x;
    const int p    = bid >> 5;
    const int slab = (bid & 31) * 16;
    const int t = threadIdx.x;
    const int wv = t >> 6, lane = t & 63;
    const int lr = lane & 15, lg = lane >> 4, lk = lg * 8;
    const int c0 = wv * 64;

    {   // phase 1: fc (replicated)
        f32x4 acc[4];
#pragma unroll
        for (int j = 0; j < 4; ++j) acc[j] = (f32x4){0.f, 0.f, 0.f, 0.f};
        const float* Aq = qf + (slab + lr) * HDIM + lk;
#pragma unroll
        for (int ks = 0; ks < 8; ++ks) {
            const float4 a0 = *(const float4*)&Aq[ks * 32];
            const float4 a1 = *(const float4*)&Aq[ks * 32 + 4];
            bf16x8 a;
            a[0] = (short)f2bf(a0.x); a[1] = (short)f2bf(a0.y);
            a[2] = (short)f2bf(a0.z); a[3] = (short)f2bf(a0.w);
            a[4] = (short)f2bf(a1.x); a[5] = (short)f2bf(a1.y);
            a[6] = (short)f2bf(a1.z); a[7] = (short)f2bf(a1.w);
#pragma unroll
            for (int j = 0; j < 4; ++j) {
                const bf16x8 b = *(const bf16x8*)&fcWt[(c0 + j * 16 + lr) * HDIM + ks * 32 + lk];
                acc[j] = __builtin_amdgcn_mfma_f32_16x16x32_bf16(a, b, acc[j], 0, 0, 0);
            }
        }
#pragma unroll
        for (int j = 0; j < 4; ++j) {
            const int col = c0 + j * 16 + lr;
            const float bbv = fcb[col];
#pragma unroll
            for (int rg = 0; rg < 4; ++rg) {
                const float o = fmaxf(acc[j][rg] + bbv, 0.f);
                if (p == 0) x[(slab + lg * 4 + rg) * HDIM + col] = o;
                xpan[(lg * 4 + rg) * XPS + col] = f2bf(o);
            }
        }
    }
    __syncthreads();
    const ushort* Wt = (p == 0) ? WqT : (p == 1) ? WkT : WvT;
    const float*  bb = (p == 0) ? bq  : (p == 1) ? bk  : bv;
    qkv_one(xpan, Wt, bb, p, slab, c0, lr, lg, lk, q16, k16, vT16);
}

// ---------------------------------------------------------------------------
// attn_fused: unchanged (proven at 109.7). 128 blocks x 256 thr.
// ---------------------------------------------------------------------------
__global__ __launch_bounds__(256) void attn_fused(
    const ushort* __restrict__ q16, const ushort* __restrict__ k16,
    const ushort* __restrict__ vT16, const float* __restrict__ dist,
    const float* __restrict__ dwraw, const float* __restrict__ inv_cs,
    ushort* __restrict__ ao16)
{
    __shared__ __align__(16) ushort P_lds[16 * PSTR];
    __shared__ __align__(16) float exch[4][16][64];
    __shared__ float rmax[4][16];
    __shared__ float psums[4][16];

    const int bid = blockIdx.x;
    const int h  = bid >> 5;
    const int n0 = (bid & 31) * 16;
    const int t  = threadIdx.x;
    const int wv = t >> 6, lane = t & 63;
    const int lr = lane & 15, lg = lane >> 4, lk = lg * 8;
    const int mW = wv * 128;

    const ushort* Qrow = q16 + (n0 + lr) * HDIM + h * DKH + lk;
    const bf16x8 a0 = *(const bf16x8*)&Qrow[0];
    const bf16x8 a1 = *(const bf16x8*)&Qrow[32];

    f32x4 accs[8];
#pragma unroll
    for (int cg = 0; cg < 8; ++cg) accs[cg] = (f32x4){0.f, 0.f, 0.f, 0.f};
#pragma unroll
    for (int cg = 0; cg < 8; ++cg) {
        const ushort* Brow = k16 + (mW + cg * 16 + lr) * HDIM + h * DKH + lk;
        accs[cg] = __builtin_amdgcn_mfma_f32_16x16x32_bf16(
            a0, *(const bf16x8*)&Brow[0], accs[cg], 0, 0, 0);
        accs[cg] = __builtin_amdgcn_mfma_f32_16x16x32_bf16(
            a1, *(const bf16x8*)&Brow[32], accs[cg], 0, 0, 0);
    }

    float s[8][4];
#pragma unroll
    for (int cg = 0; cg < 8; ++cg) {
        const int m = mW + cg * 16 + lr;
        const float ic = (h == 0) ? inv_cs[m] : 0.f;
#pragma unroll
        for (int rg = 0; rg < 4; ++rg) {
            const int n = n0 + lg * 4 + rg;
            float b = 0.f;
            if (h == 0)      b = dwraw[n * NTOK + m] * ic;
            else if (h == 1) b = -dist[n * NTOK + m];
            s[cg][rg] = accs[cg][rg] * 0.125f + b;
        }
    }

    float mx[4];
#pragma unroll
    for (int rg = 0; rg < 4; ++rg) {
        float m = s[0][rg];
#pragma unroll
        for (int cg = 1; cg < 8; ++cg) m = fmaxf(m, s[cg][rg]);
#pragma unroll
        for (int o = 1; o < 16; o <<= 1) m = fmaxf(m, __shfl_xor(m, o));
        mx[rg] = m;
    }
    if (lr == 0)
#pragma unroll
        for (int rg = 0; rg < 4; ++rg) rmax[wv][lg * 4 + rg] = mx[rg];
    __syncthreads();
    float mxf[4];
#pragma unroll
    for (int rg = 0; rg < 4; ++rg) {
        const int row = lg * 4 + rg;
        mxf[rg] = fmaxf(fmaxf(rmax[0][row], rmax[1][row]),
                        fmaxf(rmax[2][row], rmax[3][row]));
    }

    float ps[4] = {0.f, 0.f, 0.f, 0.f};
#pragma unroll
    for (int cg = 0; cg < 8; ++cg)
#pragma unroll
        for (int rg = 0; rg < 4; ++rg) {
            const float e = __expf(s[cg][rg] - mxf[rg]);
            ps[rg] += e;
            P_lds[(lg * 4 + rg) * PSTR + mW + cg * 16 + lr] = f2bf(e);
        }
#pragma unroll
    for (int rg = 0; rg < 4; ++rg) {
#pragma unroll
        for (int o = 1; o < 16; o <<= 1) ps[rg] += __shfl_xor(ps[rg], o);
    }
    if (lr == 0)
#pragma unroll
        for (int rg = 0; rg < 4; ++rg) psums[wv][lg * 4 + rg] = ps[rg];
    __syncthreads();

    f32x4 acco[4];
#pragma unroll
    for (int db = 0; db < 4; ++db) acco[db] = (f32x4){0.f, 0.f, 0.f, 0.f};
#pragma unroll
    for (int c = 0; c < 4; ++c) {
        const bf16x8 pa = *(const bf16x8*)&P_lds[lr * PSTR + mW + c * 32 + lk];
#pragma unroll
        for (int db = 0; db < 4; ++db) {
            const bf16x8 b = *(const bf16x8*)
                &vT16[(h * DKH + db * 16 + lr) * NTOK + mW + c * 32 + lk];
            acco[db] = __builtin_amdgcn_mfma_f32_16x16x32_bf16(pa, b, acco[db], 0, 0, 0);
        }
    }
#pragma unroll
    for (int db = 0; db < 4; ++db)
#pragma unroll
        for (int rg = 0; rg < 4; ++rg)
            exch[wv][lg * 4 + rg][db * 16 + lr] = acco[db][rg];
    __syncthreads();

    {
        const int r = t >> 4, d4 = t & 15;
        f32x4 sum = *(const f32x4*)&exch[0][r][d4 * 4];
        sum += *(const f32x4*)&exch[1][r][d4 * 4];
        sum += *(const f32x4*)&exch[2][r][d4 * 4];
        sum += *(const f32x4*)&exch[3][r][d4 * 4];
        const float inv = 1.0f / (psums[0][r] + psums[1][r] + psums[2][r] + psums[3][r]);
        ushort4 o = {f2bf(sum.x * inv), f2bf(sum.y * inv),
                     f2bf(sum.z * inv), f2bf(sum.w * inv)};
        *(ushort4*)&ao16[(n0 + r) * HDIM + h * DKH + d4 * 4] = o;
    }
}

// ---------------------------------------------------------------------------
// oproj+LN phase (shared, proven round 11): normalized values left in acc.
// ---------------------------------------------------------------------------
__device__ __forceinline__ void oprojln_phase(
    const ushort* __restrict__ ao16, const ushort* __restrict__ WoT,
    const float* __restrict__ bo, const float* __restrict__ gamma,
    const float* __restrict__ beta, const float* __restrict__ x,
    int slab, int c0, int wv, int lr, int lg, int lk,
    float red[4][16], f32x4 acc[4])
{
    const ushort* Arow = ao16 + (slab + lr) * HDIM + lk;
#pragma unroll
    for (int j = 0; j < 4; ++j) acc[j] = (f32x4){0.f, 0.f, 0.f, 0.f};
#pragma unroll
    for (int ks = 0; ks < 8; ++ks) {
        const bf16x8 a = *(const bf16x8*)&Arow[ks * 32];
#pragma unroll
        for (int j = 0; j < 4; ++j) {
            const bf16x8 b = *(const bf16x8*)&WoT[(c0 + j * 16 + lr) * HDIM + ks * 32 + lk];
            acc[j] = __builtin_amdgcn_mfma_f32_16x16x32_bf16(a, b, acc[j], 0, 0, 0);
        }
    }
#pragma unroll
    for (int j = 0; j < 4; ++j) {
        const int col = c0 + j * 16 + lr;
        const float bc = bo[col];
#pragma unroll
        for (int rg = 0; rg < 4; ++rg)
            acc[j][rg] += bc + x[(slab + lg * 4 + rg) * HDIM + col];
    }

    float sm[4];
#pragma unroll
    for (int rg = 0; rg < 4; ++rg) {
        float s = 0.f;
#pragma unroll
        for (int j = 0; j < 4; ++j) s += acc[j][rg];
#pragma unroll
        for (int o = 1; o < 16; o <<= 1) s += __shfl_xor(s, o);
        sm[rg] = s;
    }
    if (lr == 0)
#pragma unroll
        for (int rg = 0; rg < 4; ++rg) red[wv][lg * 4 + rg] = sm[rg];
    __syncthreads();
    float mean[4];
#pragma unroll
    for (int rg = 0; rg < 4; ++rg) {
        const int row = lg * 4 + rg;
        mean[rg] = (red[0][row] + red[1][row] + red[2][row] + red[3][row]) * (1.f / 256.f);
    }
    __syncthreads();

#pragma unroll
    for (int rg = 0; rg < 4; ++rg) {
        float s2 = 0.f;
#pragma unroll
        for (int j = 0; j < 4; ++j) {
            const float c = acc[j][rg] - mean[rg];
            s2 += c * c;
        }
#pragma unroll
        for (int o = 1; o < 16; o <<= 1) s2 += __shfl_xor(s2, o);
        sm[rg] = s2;
    }
    if (lr == 0)
#pragma unroll
        for (int rg = 0; rg < 4; ++rg) red[wv][lg * 4 + rg] = sm[rg];
    __syncthreads();
    float rstd[4];
#pragma unroll
    for (int rg = 0; rg < 4; ++rg) {
        const int row = lg * 4 + rg;
        const float var = (red[0][row] + red[1][row] + red[2][row] + red[3][row]) * (1.f / 256.f);
        rstd[rg] = rsqrtf(var + 1e-5f);
    }
#pragma unroll
    for (int j = 0; j < 4; ++j) {
        const int col = c0 + j * 16 + lr;
        const float gg = gamma[col], bv = beta[col];
#pragma unroll
        for (int rg = 0; rg < 4; ++rg)
            acc[j][rg] = (acc[j][rg] - mean[rg]) * rstd[rg] * gg + bv;
    }
}

// ---------------------------------------------------------------------------
// oprojqkv: 96 blocks. p = bid>>5, slab = (bid&31)*16. Phase 1 (replicated):
// oproj+resid+LN -> xpan (+ x f32 if p==0). Phase 2: qkv problem p (L+1).
// ---------------------------------------------------------------------------
__global__ __launch_bounds__(256) void oprojqkv(
    const ushort* __restrict__ ao16, const ushort* __restrict__ WoT,
    const float* __restrict__ bo, const float* __restrict__ gamma,
    const float* __restrict__ beta,
    const ushort* __restrict__ WqT, const float* __restrict__ bq,
    const ushort* __restrict__ WkT, const float* __restrict__ bk,
    const ushort* __restrict__ WvT, const float* __restrict__ bv,
    float* __restrict__ x, ushort* __restrict__ q16,
    ushort* __restrict__ k16, ushort* __restrict__ vT16)
{
    __shared__ __align__(16) ushort xpan[16 * XPS];
    __shared__ float red[4][16];
    const int bid  = blockIdx.x;
    const int p    = bid >> 5;
    const int slab = (bid & 31) * 16;
    const int t = threadIdx.x;
    const int wv = t >> 6, lane = t & 63;
    const int lr = lane & 15, lg = lane >> 4, lk = lg * 8;
    const int c0 = wv * 64;

    f32x4 acc[4];
    oprojln_phase(ao16, WoT, bo, gamma, beta, x, slab, c0, wv, lr, lg, lk, red, acc);
#pragma unroll
    for (int j = 0; j < 4; ++j) {
        const int col = c0 + j * 16 + lr;
#pragma unroll
        for (int rg = 0; rg < 4; ++rg) {
            if (p == 0) x[(slab + lg * 4 + rg) * HDIM + col] = acc[j][rg];
            xpan[(lg * 4 + rg) * XPS + col] = f2bf(acc[j][rg]);
        }
    }
    __syncthreads();
    const ushort* Wt = (p == 0) ? WqT : (p == 1) ? WkT : WvT;
    const float*  bb = (p == 0) ? bq  : (p == 1) ? bk  : bv;
    qkv_one(xpan, Wt, bb, p, slab, c0, lr, lg, lk, q16, k16, vT16);
}

// ---------------------------------------------------------------------------
// oprojmlpU: 64 blocks. p = bid>>5 in {0,1}, slab = (bid&31)*16.
// Phase 1 (replicated): oproj+resid+LN (L1) -> xpan. Phase 2: o_p =
// relu(x@m_pW+b_p) -> opan. Phase 3: U_p = o_p@cW1_p (+cb1 if p==0) -> f32.
// ---------------------------------------------------------------------------
__global__ __launch_bounds__(256) void oprojmlpU(
    const ushort* __restrict__ ao16, const ushort* __restrict__ WoT,
    const float* __restrict__ bo, const float* __restrict__ gamma,
    const float* __restrict__ beta,
    const ushort* __restrict__ m1WT, const float* __restrict__ m1b,
    const ushort* __restrict__ m2WT, const float* __restrict__ m2b,
    const ushort* __restrict__ cW1aT, const float* __restrict__ cb1,
    const ushort* __restrict__ cW1bT,
    const float* __restrict__ x, float* __restrict__ U1, float* __restrict__ U2)
{
    __shared__ __align__(16) ushort xpan[16 * XPS];
    __shared__ __align__(16) ushort opan[16 * XPS];
    __shared__ float red[4][16];
    const int bid  = blockIdx.x;
    const int p    = bid >> 5;
    const int slab = (bid & 31) * 16;
    const int t = threadIdx.x;
    const int wv = t >> 6, lane = t & 63;
    const int lr = lane & 15, lg = lane >> 4, lk = lg * 8;
    const int c0 = wv * 64;

    f32x4 acc[4];
    oprojln_phase(ao16, WoT, bo, gamma, beta, x, slab, c0, wv, lr, lg, lk, red, acc);
#pragma unroll
    for (int j = 0; j < 4; ++j) {
        const int col = c0 + j * 16 + lr;
#pragma unroll
        for (int rg = 0; rg < 4; ++rg)
            xpan[(lg * 4 + rg) * XPS + col] = f2bf(acc[j][rg]);
    }
    __syncthreads();

    {   // phase 2: mlp problem p
        const ushort* Wt = p ? m2WT : m1WT;
        const float*  bb = p ? m2b  : m1b;
        const ushort* Ap = xpan + lr * XPS + lk;
        f32x4 a2[4];
#pragma unroll
        for (int j = 0; j < 4; ++j) a2[j] = (f32x4){0.f, 0.f, 0.f, 0.f};
#pragma unroll
        for (int ks = 0; ks < 8; ++ks) {
            const bf16x8 a = *(const bf16x8*)&Ap[ks * 32];
#pragma unroll
            for (int j = 0; j < 4; ++j) {
                const bf16x8 b = *(const bf16x8*)&Wt[(c0 + j * 16 + lr) * HDIM + ks * 32 + lk];
                a2[j] = __builtin_amdgcn_mfma_f32_16x16x32_bf16(a, b, a2[j], 0, 0, 0);
            }
        }
#pragma unroll
        for (int j = 0; j < 4; ++j) {
            const int col = c0 + j * 16 + lr;
            const float bbv = bb[col];
#pragma unroll
            for (int rg = 0; rg < 4; ++rg)
                opan[(lg * 4 + rg) * XPS + col] = f2bf(fmaxf(a2[j][rg] + bbv, 0.f));
        }
    }
    __syncthreads();

    {   // phase 3: U problem p
        const ushort* Wt = p ? cW1bT : cW1aT;
        float* U         = p ? U2 : U1;
        const ushort* Ao = opan + lr * XPS + lk;
        f32x4 a2[4];
#pragma unroll
        for (int j = 0; j < 4; ++j) a2[j] = (f32x4){0.f, 0.f, 0.f, 0.f};
#pragma unroll
        for (int ks = 0; ks < 8; ++ks) {
            const bf16x8 a = *(const bf16x8*)&Ao[ks * 32];
#pragma unroll
            for (int j = 0; j < 4; ++j) {
                const bf16x8 b = *(const bf16x8*)&Wt[(c0 + j * 16 + lr) * HDIM + ks * 32 + lk];
                a2[j] = __builtin_amdgcn_mfma_f32_16x16x32_bf16(a, b, a2[j], 0, 0, 0);
            }
        }
#pragma unroll
        for (int j = 0; j < 4; ++j) {
            const int col = c0 + j * 16 + lr;
            const float bbv = (p == 0) ? cb1[col] : 0.f;
#pragma unroll
            for (int rg = 0; rg < 4; ++rg)
                U[(slab + lg * 4 + rg) * HDIM + col] = a2[j][rg] + bbv;
        }
    }
}

// ---------------------------------------------------------------------------
// pair_cls: 32x32 tile, 2x2 per thread, TL copies. (f32 inputs, proven)
// ---------------------------------------------------------------------------
__global__ __launch_bounds__(256) void pair_cls(const float* __restrict__ U1,
                                                const float* __restrict__ U2,
                                                const float* __restrict__ W2,
                                                const float* __restrict__ b2,
                                                float* __restrict__ out)
{
    __shared__ __align__(16) float u1s[32][260];
    __shared__ __align__(16) float u2s[32][260];
    __shared__ __align__(16) float w2s[256];
    const int t  = threadIdx.x;
    const int n0 = blockIdx.y * 32, m0 = blockIdx.x * 32;

    for (int i = t; i < 32 * 64; i += 256) {
        const int r = i >> 6, c4 = i & 63;
        *(float4*)&u1s[r][c4 * 4] = *(const float4*)&U1[(n0 + r) * HDIM + c4 * 4];
        *(float4*)&u2s[r][c4 * 4] = *(const float4*)&U2[(m0 + r) * HDIM + c4 * 4];
    }
    if (t < 64) *(float4*)&w2s[t * 4] = *(const float4*)&W2[t * 4];
    __syncthreads();

    const int tx = t & 15, ty = t >> 4;
    float acc[2][2] = {};
    for (int h4 = 0; h4 < 64; ++h4) {
        const float4 a0 = *(const float4*)&u1s[ty * 2][h4 * 4];
        const float4 a1 = *(const float4*)&u1s[ty * 2 + 1][h4 * 4];
        const float4 b0 = *(const float4*)&u2s[tx * 2][h4 * 4];
        const float4 b1 = *(const float4*)&u2s[tx * 2 + 1][h4 * 4];
        const float4 w  = *(const float4*)&w2s[h4 * 4];
#define RT(A, B) fmaxf((A) + (B), 0.f)
        acc[0][0] += RT(a0.x,b0.x)*w.x + RT(a0.y,b0.y)*w.y + RT(a0.z,b0.z)*w.z + RT(a0.w,b0.w)*w.w;
        acc[0][1] += RT(a0.x,b1.x)*w.x + RT(a0.y,b1.y)*w.y + RT(a0.z,b1.z)*w.z + RT(a0.w,b1.w)*w.w;
        acc[1][0] += RT(a1.x,b0.x)*w.x + RT(a1.y,b0.y)*w.y + RT(a1.z,b0.z)*w.z + RT(a1.w,b0.w)*w.w;
        acc[1][1] += RT(a1.x,b1.x)*w.x + RT(a1.y,b1.y)*w.y + RT(a1.z,b1.z)*w.z + RT(a1.w,b1.w)*w.w;
#undef RT
    }
    const float bbv = b2[0];
#pragma unroll
    for (int ii = 0; ii < 2; ++ii)
#pragma unroll
        for (int jj = 0; jj < 2; ++jj) {
            const float val = acc[ii][jj] + bbv;
            const int n = n0 + ty * 2 + ii;
            const int m = m0 + tx * 2 + jj;
#pragma unroll
            for (int tl = 0; tl < TLEN; ++tl)
                out[tl * NTOK * NTOK + n * NTOK + m] = val;
        }
}

// ---------------------------------------------------------------------------
extern "C" void kernel_launch(void* const* d_in, const int* in_sizes, int n_in,
                              void* d_out, int out_size, void* d_ws, size_t ws_size,
                              hipStream_t stream)
{
    const float* hs   = (const float*)d_in[0];
    const float* qf   = hs + 5 * NTOK * HDIM;
    const float* alp  = (const float*)d_in[1];
    const float* pl   = alp + 5 * NTOK * 33;
    const float* fc_W = (const float*)d_in[2];
    const float* fc_b = (const float*)d_in[3];
    const float* Wq   = (const float*)d_in[4];
    const float* bq   = (const float*)d_in[5];
    const float* Wk   = (const float*)d_in[6];
    const float* bk   = (const float*)d_in[7];
    const float* Wv   = (const float*)d_in[8];
    const float* bv   = (const float*)d_in[9];
    const float* Wo   = (const float*)d_in[10];
    const float* bo   = (const float*)d_in[11];
    const float* lng  = (const float*)d_in[12];
    const float* lnb  = (const float*)d_in[13];
    const float* m1W  = (const float*)d_in[14];
    const float* m1b  = (const float*)d_in[15];
    const float* m2W  = (const float*)d_in[16];
    const float* m2b  = (const float*)d_in[17];
    const float* cW1  = (const float*)d_in[18];
    const float* cb1  = (const float*)d_in[19];
    const float* cW2  = (const float*)d_in[20];
    const float* cb2  = (const float*)d_in[21];
    float* out = (float*)d_out;

    const int NN  = NTOK * NTOK;
    const int NH_ = NTOK * HDIM;
    float* ws     = (float*)d_ws;
    float* dist   = ws;                       // NN
    float* dwraw  = ws + NN;                  // NN
    float* inv_cs = ws + 2 * NN;              // 512
    float* x      = ws + 2 * NN + 512;        // NH
    float* U1     = x + NH_;                  // NH
    float* U2     = U1 + NH_;                 // NH
    ushort* u16   = (ushort*)(U2 + NH_);
    ushort* wpk   = u16;                      // 13 * WSZ
    ushort* q16   = wpk + 13 * WSZ;           // NH
    ushort* k16   = q16 + NH_;                // NH
    ushort* vT16  = k16 + NH_;                // NH ([d][m])
    ushort* ao16  = vT16 + NH_;               // NH

    PKArg pk;
    pk.w[0]  = fc_W;
    pk.w[1]  = Wq;  pk.w[2]  = Wq + WSZ;
    pk.w[3]  = Wk;  pk.w[4]  = Wk + WSZ;
    pk.w[5]  = Wv;  pk.w[6]  = Wv + WSZ;
    pk.w[7]  = Wo;  pk.w[8]  = Wo + WSZ;
    pk.w[9]  = m1W; pk.w[10] = m2W;
    pk.w[11] = cW1; pk.w[12] = cW1 + WSZ;
    pk.pl = pl;
    pk.wpk = wpk;
    pk.dist = dist; pk.dwraw = dwraw; pk.inv_cs = inv_cs;
    pack_kernel<<<216, 256, 0, stream>>>(pk);

    // fc (replicated x3) + qkv (L0)
    fcqkv<<<96, 256, 0, stream>>>(
        qf, wpk + 0 * WSZ, fc_b,
        wpk + 1 * WSZ, bq, wpk + 3 * WSZ, bk, wpk + 5 * WSZ, bv,
        x, q16, k16, vT16);

    attn_fused<<<128, 256, 0, stream>>>(q16, k16, vT16, dist, dwraw, inv_cs, ao16);

    // oproj+LN (L0, replicated x3) -> qkv (L1)
    oprojqkv<<<96, 256, 0, stream>>>(
        ao16, wpk + 7 * WSZ, bo, lng, lnb,
        wpk + 2 * WSZ, bq + HDIM, wpk + 4 * WSZ, bk + HDIM,
        wpk + 6 * WSZ, bv + HDIM,
        x, q16, k16, vT16);

    attn_fused<<<128, 256, 0, stream>>>(q16, k16, vT16, dist, dwraw, inv_cs, ao16);

    // oproj+LN (L1, replicated x2) -> mlp_p -> U_p
    oprojmlpU<<<64, 256, 0, stream>>>(
        ao16, wpk + 8 * WSZ, bo + HDIM, lng + HDIM, lnb + HDIM,
        wpk + 9 * WSZ, m1b, wpk + 10 * WSZ, m2b,
        wpk + 11 * WSZ, cb1, wpk + 12 * WSZ,
        x, U1, U2);

    pair_cls<<<dim3(16, 16), 256, 0, stream>>>(U1, U2, cW2, cb2, out);
}

// Round 13
// 97.694 us; speedup vs baseline: 1.5685x; 1.1350x over previous
//
#include <hip/hip_runtime.h>
#include <math.h>

// ---------------------------------------------------------------------------
// SpatialProximityHead on MI355X — round 12: widened 7-dispatch pipeline.
// attn 512thr/8-wave; fused GEMM kernels 192/128 blocks via (problem x
// col-half) replication; x double-buffered (race fix).
// pack(216) -> fcqkv(192) -> attn(128x512) -> oprojqkv(192) -> attn
//           -> oprojmlpU(128) -> pair(256)
// ---------------------------------------------------------------------------

#define NTOK 512
#define HDIM 256
#define DKH  64
#define NHEAD 4
#define TLEN 6
#define WSZ  65536
#define PSTR 520   // attn P_lds ushort stride
#define XPS  264   // LDS panel ushort stride

typedef __attribute__((ext_vector_type(8))) short bf16x8;
typedef __attribute__((ext_vector_type(4))) float f32x4;

__device__ __forceinline__ ushort f2bf(float f)
{
    unsigned u = __builtin_bit_cast(unsigned, f);
    u += 0x7FFFu + ((u >> 16) & 1u);     // RNE
    return (ushort)(u >> 16);
}

struct PKArg {
    const float* w[13];
    const float* pl;
    ushort* wpk;
    float *dist, *dwraw, *inv_cs;
};

// ---------------------------------------------------------------------------
// pack: 0-207 weight 64x64 transpose tiles ([col][k] bf16); 208-215 dist prep.
// ---------------------------------------------------------------------------
__global__ __launch_bounds__(256) void pack_kernel(PKArg p)
{
    __shared__ __align__(16) ushort smu[64 * 72];
    const int bid = blockIdx.x;
    const int t   = threadIdx.x;

    if (bid < 208) {
        const int mat  = bid >> 4;
        const int tile = bid & 15;
        const int k0   = (tile >> 2) * 64;
        const int c0   = (tile & 3) * 64;
        const float* W = p.w[mat];
#pragma unroll
        for (int j = 0; j < 4; ++j) {
            const int i  = t + j * 256;
            const int r  = i >> 4, c4 = i & 15;
            const float4 v4 = *(const float4*)&W[(k0 + r) * HDIM + c0 + c4 * 4];
            smu[(c4 * 4 + 0) * 72 + r] = f2bf(v4.x);
            smu[(c4 * 4 + 1) * 72 + r] = f2bf(v4.y);
            smu[(c4 * 4 + 2) * 72 + r] = f2bf(v4.z);
            smu[(c4 * 4 + 3) * 72 + r] = f2bf(v4.w);
        }
        __syncthreads();
#pragma unroll
        for (int j = 0; j < 2; ++j) {
            const int i  = t + j * 256;
            const int cr = i >> 3, kk = i & 7;
            const uint4 v = *(const uint4*)&smu[cr * 72 + kk * 8];
            *(uint4*)&p.wpk[mat * WSZ + (c0 + cr) * HDIM + k0 + kk * 8] = v;
        }
    } else {
        float* smf = (float*)smu;
        float* qe  = smf;            // [512][3]
        float* red = smf + 1536;     // [4][64]
        const int item = bid - 208;
        for (int i = t; i < 512; i += 256) {
            qe[i * 3 + 0] = p.pl[i * 33 + 30];
            qe[i * 3 + 1] = p.pl[i * 33 + 31];
            qe[i * 3 + 2] = p.pl[i * 33 + 32];
        }
        __syncthreads();
        const int m   = item * 64 + (t & 63);
        const int nch = t >> 6;
        const float kx = p.pl[m * 33 + 0], ky = p.pl[m * 33 + 1], kz = p.pl[m * 33 + 2];
        float cs = 0.f;
        for (int n = nch * 128; n < nch * 128 + 128; ++n) {
            const float dx = kx - qe[n * 3 + 0];
            const float dy = ky - qe[n * 3 + 1];
            const float dz = kz - qe[n * 3 + 2];
            const float dd = sqrtf(dx * dx + dy * dy + dz * dz);
            const float w  = 1.0f / (dd + 0.01f);
            p.dist[n * NTOK + m]  = dd;
            p.dwraw[n * NTOK + m] = w;
            cs += w;
        }
        red[nch * 64 + (t & 63)] = cs;
        __syncthreads();
        if (t < 64)
            p.inv_cs[item * 64 + t] =
                1.0f / (red[t] + red[64 + t] + red[128 + t] + red[192 + t]);
    }
}

// ---------------------------------------------------------------------------
// qkv_one2: one qkv problem, 2 col-groups starting at c0. prob: 0->q16,
// 1->k16 (row-major), 2->vT16 (transposed).
// ---------------------------------------------------------------------------
__device__ __forceinline__ void qkv_one2(
    const ushort* __restrict__ xpan, const ushort* __restrict__ Wt,
    const float* __restrict__ bb, int prob,
    int slab, int c0, int lr, int lg, int lk,
    ushort* __restrict__ q16, ushort* __restrict__ k16,
    ushort* __restrict__ vT16)
{
    const ushort* Ap = xpan + lr * XPS + lk;
    f32x4 acc[2];
    acc[0] = (f32x4){0.f, 0.f, 0.f, 0.f};
    acc[1] = (f32x4){0.f, 0.f, 0.f, 0.f};
#pragma unroll
    for (int ks = 0; ks < 8; ++ks) {
        const bf16x8 a = *(const bf16x8*)&Ap[ks * 32];
#pragma unroll
        for (int j = 0; j < 2; ++j) {
            const bf16x8 b = *(const bf16x8*)&Wt[(c0 + j * 16 + lr) * HDIM + ks * 32 + lk];
            acc[j] = __builtin_amdgcn_mfma_f32_16x16x32_bf16(a, b, acc[j], 0, 0, 0);
        }
    }
#pragma unroll
    for (int j = 0; j < 2; ++j) {
        const int col = c0 + j * 16 + lr;
        const float bv2 = bb[col];
        if (prob < 2) {
            ushort* dst = (prob == 0) ? q16 : k16;
#pragma unroll
            for (int rg = 0; rg < 4; ++rg)
                dst[(slab + lg * 4 + rg) * HDIM + col] = f2bf(acc[j][rg] + bv2);
        } else {
            ushort4 s = {f2bf(acc[j][0] + bv2), f2bf(acc[j][1] + bv2),
                         f2bf(acc[j][2] + bv2), f2bf(acc[j][3] + bv2)};
            *(ushort4*)&vT16[col * NTOK + slab + lg * 4] = s;
        }
    }
}

// ---------------------------------------------------------------------------
// fcqkv: 192 blocks. p6 = bid>>5 (0..5): prob = p6>>1, ch = p6&1.
// Phase 1 (replicated): x = relu(qf@fcW+fcb) -> xpan (+ xa f32 if p6==0).
// Phase 2: qkv problem prob, col-half ch.
// ---------------------------------------------------------------------------
__global__ __launch_bounds__(256) void fcqkv(
    const float* __restrict__ qf, const ushort* __restrict__ fcWt,
    const float* __restrict__ fcb,
    const ushort* __restrict__ WqT, const float* __restrict__ bq,
    const ushort* __restrict__ WkT, const float* __restrict__ bk,
    const ushort* __restrict__ WvT, const float* __restrict__ bv,
    float* __restrict__ xa, ushort* __restrict__ q16,
    ushort* __restrict__ k16, ushort* __restrict__ vT16)
{
    __shared__ __align__(16) ushort xpan[16 * XPS];
    const int bid  = blockIdx.x;
    const int p6   = bid >> 5;
    const int slab = (bid & 31) * 16;
    const int t = threadIdx.x;
    const int wv = t >> 6, lane = t & 63;
    const int lr = lane & 15, lg = lane >> 4, lk = lg * 8;
    const int c0 = wv * 64;

    {   // phase 1: fc (replicated)
        f32x4 acc[4];
#pragma unroll
        for (int j = 0; j < 4; ++j) acc[j] = (f32x4){0.f, 0.f, 0.f, 0.f};
        const float* Aq = qf + (slab + lr) * HDIM + lk;
#pragma unroll
        for (int ks = 0; ks < 8; ++ks) {
            const float4 a0 = *(const float4*)&Aq[ks * 32];
            const float4 a1 = *(const float4*)&Aq[ks * 32 + 4];
            bf16x8 a;
            a[0] = (short)f2bf(a0.x); a[1] = (short)f2bf(a0.y);
            a[2] = (short)f2bf(a0.z); a[3] = (short)f2bf(a0.w);
            a[4] = (short)f2bf(a1.x); a[5] = (short)f2bf(a1.y);
            a[6] = (short)f2bf(a1.z); a[7] = (short)f2bf(a1.w);
#pragma unroll
            for (int j = 0; j < 4; ++j) {
                const bf16x8 b = *(const bf16x8*)&fcWt[(c0 + j * 16 + lr) * HDIM + ks * 32 + lk];
                acc[j] = __builtin_amdgcn_mfma_f32_16x16x32_bf16(a, b, acc[j], 0, 0, 0);
            }
        }
#pragma unroll
        for (int j = 0; j < 4; ++j) {
            const int col = c0 + j * 16 + lr;
            const float bbv = fcb[col];
#pragma unroll
            for (int rg = 0; rg < 4; ++rg) {
                const float o = fmaxf(acc[j][rg] + bbv, 0.f);
                if (p6 == 0) xa[(slab + lg * 4 + rg) * HDIM + col] = o;
                xpan[(lg * 4 + rg) * XPS + col] = f2bf(o);
            }
        }
    }
    __syncthreads();
    const int prob = p6 >> 1, ch = p6 & 1;
    const ushort* Wt = (prob == 0) ? WqT : (prob == 1) ? WkT : WvT;
    const float*  bb = (prob == 0) ? bq  : (prob == 1) ? bk  : bv;
    qkv_one2(xpan, Wt, bb, prob, slab, ch * 128 + wv * 32, lr, lg, lk,
             q16, k16, vT16);
}

// ---------------------------------------------------------------------------
// attn_fused: 128 blocks x 512 thr (8 waves). Wave wv owns keys wv*64..+64.
// S=qk^T/8+bias (MFMA), cross-wave softmax via LDS, P->bf16->LDS,
// PV (MFMA vs vT16), 8-way combine with 1/rowsum.
// ---------------------------------------------------------------------------
__global__ __launch_bounds__(512) void attn_fused(
    const ushort* __restrict__ q16, const ushort* __restrict__ k16,
    const ushort* __restrict__ vT16, const float* __restrict__ dist,
    const float* __restrict__ dwraw, const float* __restrict__ inv_cs,
    ushort* __restrict__ ao16)
{
    __shared__ __align__(16) ushort P_lds[16 * PSTR];   // 16.6 KB
    __shared__ __align__(16) float exch[8][16][64];     // 32 KB
    __shared__ float rmax[8][16];
    __shared__ float psums[8][16];

    const int bid = blockIdx.x;
    const int h  = bid >> 5;
    const int n0 = (bid & 31) * 16;
    const int t  = threadIdx.x;
    const int wv = t >> 6, lane = t & 63;
    const int lr = lane & 15, lg = lane >> 4, lk = lg * 8;
    const int mW = wv * 64;

    const ushort* Qrow = q16 + (n0 + lr) * HDIM + h * DKH + lk;
    const bf16x8 a0 = *(const bf16x8*)&Qrow[0];
    const bf16x8 a1 = *(const bf16x8*)&Qrow[32];

    // ---- S = Q @ K^T (16 x 64 per wave) ----
    f32x4 accs[4];
#pragma unroll
    for (int cg = 0; cg < 4; ++cg) accs[cg] = (f32x4){0.f, 0.f, 0.f, 0.f};
#pragma unroll
    for (int cg = 0; cg < 4; ++cg) {
        const ushort* Brow = k16 + (mW + cg * 16 + lr) * HDIM + h * DKH + lk;
        accs[cg] = __builtin_amdgcn_mfma_f32_16x16x32_bf16(
            a0, *(const bf16x8*)&Brow[0], accs[cg], 0, 0, 0);
        accs[cg] = __builtin_amdgcn_mfma_f32_16x16x32_bf16(
            a1, *(const bf16x8*)&Brow[32], accs[cg], 0, 0, 0);
    }

    // ---- scale + bias ----
    float s[4][4];
#pragma unroll
    for (int cg = 0; cg < 4; ++cg) {
        const int m = mW + cg * 16 + lr;
        const float ic = (h == 0) ? inv_cs[m] : 0.f;
#pragma unroll
        for (int rg = 0; rg < 4; ++rg) {
            const int n = n0 + lg * 4 + rg;
            float b = 0.f;
            if (h == 0)      b = dwraw[n * NTOK + m] * ic;
            else if (h == 1) b = -dist[n * NTOK + m];
            s[cg][rg] = accs[cg][rg] * 0.125f + b;
        }
    }

    // ---- row max ----
    float mx[4];
#pragma unroll
    for (int rg = 0; rg < 4; ++rg) {
        float m = fmaxf(fmaxf(s[0][rg], s[1][rg]), fmaxf(s[2][rg], s[3][rg]));
#pragma unroll
        for (int o = 1; o < 16; o <<= 1) m = fmaxf(m, __shfl_xor(m, o));
        mx[rg] = m;
    }
    if (lr == 0)
#pragma unroll
        for (int rg = 0; rg < 4; ++rg) rmax[wv][lg * 4 + rg] = mx[rg];
    __syncthreads();
    float mxf[4];
#pragma unroll
    for (int rg = 0; rg < 4; ++rg) {
        const int row = lg * 4 + rg;
        float m = rmax[0][row];
#pragma unroll
        for (int w = 1; w < 8; ++w) m = fmaxf(m, rmax[w][row]);
        mxf[rg] = m;
    }

    // ---- exp, partial sums, P -> LDS (bf16) ----
    float ps[4] = {0.f, 0.f, 0.f, 0.f};
#pragma unroll
    for (int cg = 0; cg < 4; ++cg)
#pragma unroll
        for (int rg = 0; rg < 4; ++rg) {
            const float e = __expf(s[cg][rg] - mxf[rg]);
            ps[rg] += e;
            P_lds[(lg * 4 + rg) * PSTR + mW + cg * 16 + lr] = f2bf(e);
        }
#pragma unroll
    for (int rg = 0; rg < 4; ++rg) {
#pragma unroll
        for (int o = 1; o < 16; o <<= 1) ps[rg] += __shfl_xor(ps[rg], o);
    }
    if (lr == 0)
#pragma unroll
        for (int rg = 0; rg < 4; ++rg) psums[wv][lg * 4 + rg] = ps[rg];
    __syncthreads();

    // ---- PV over wave's own 64-key slice ----
    f32x4 acco[4];
#pragma unroll
    for (int db = 0; db < 4; ++db) acco[db] = (f32x4){0.f, 0.f, 0.f, 0.f};
#pragma unroll
    for (int c = 0; c < 2; ++c) {
        const bf16x8 pa = *(const bf16x8*)&P_lds[lr * PSTR + mW + c * 32 + lk];
#pragma unroll
        for (int db = 0; db < 4; ++db) {
            const bf16x8 b = *(const bf16x8*)
                &vT16[(h * DKH + db * 16 + lr) * NTOK + mW + c * 32 + lk];
            acco[db] = __builtin_amdgcn_mfma_f32_16x16x32_bf16(pa, b, acco[db], 0, 0, 0);
        }
    }
#pragma unroll
    for (int db = 0; db < 4; ++db)
#pragma unroll
        for (int rg = 0; rg < 4; ++rg)
            exch[wv][lg * 4 + rg][db * 16 + lr] = acco[db][rg];
    __syncthreads();

    // ---- combine 8 partials + 1/rowsum + store (2 dims/thread) ----
    {
        const int r = t >> 5, dp = (t & 31) * 2;
        float sx = 0.f, sy = 0.f, den = 0.f;
#pragma unroll
        for (int w = 0; w < 8; ++w) {
            const float2 e = *(const float2*)&exch[w][r][dp];
            sx += e.x; sy += e.y;
            den += psums[w][r];
        }
        const float inv = 1.0f / den;
        ushort2 o = {f2bf(sx * inv), f2bf(sy * inv)};
        *(ushort2*)&ao16[(n0 + r) * HDIM + h * DKH + dp] = o;
    }
}

// ---------------------------------------------------------------------------
// oproj+LN phase (proven): normalized values left in acc.
// ---------------------------------------------------------------------------
__device__ __forceinline__ void oprojln_phase(
    const ushort* __restrict__ ao16, const ushort* __restrict__ WoT,
    const float* __restrict__ bo, const float* __restrict__ gamma,
    const float* __restrict__ beta, const float* __restrict__ x,
    int slab, int c0, int wv, int lr, int lg, int lk,
    float red[4][16], f32x4 acc[4])
{
    const ushort* Arow = ao16 + (slab + lr) * HDIM + lk;
#pragma unroll
    for (int j = 0; j < 4; ++j) acc[j] = (f32x4){0.f, 0.f, 0.f, 0.f};
#pragma unroll
    for (int ks = 0; ks < 8; ++ks) {
        const bf16x8 a = *(const bf16x8*)&Arow[ks * 32];
#pragma unroll
        for (int j = 0; j < 4; ++j) {
            const bf16x8 b = *(const bf16x8*)&WoT[(c0 + j * 16 + lr) * HDIM + ks * 32 + lk];
            acc[j] = __builtin_amdgcn_mfma_f32_16x16x32_bf16(a, b, acc[j], 0, 0, 0);
        }
    }
#pragma unroll
    for (int j = 0; j < 4; ++j) {
        const int col = c0 + j * 16 + lr;
        const float bc = bo[col];
#pragma unroll
        for (int rg = 0; rg < 4; ++rg)
            acc[j][rg] += bc + x[(slab + lg * 4 + rg) * HDIM + col];
    }

    float sm[4];
#pragma unroll
    for (int rg = 0; rg < 4; ++rg) {
        float s = 0.f;
#pragma unroll
        for (int j = 0; j < 4; ++j) s += acc[j][rg];
#pragma unroll
        for (int o = 1; o < 16; o <<= 1) s += __shfl_xor(s, o);
        sm[rg] = s;
    }
    if (lr == 0)
#pragma unroll
        for (int rg = 0; rg < 4; ++rg) red[wv][lg * 4 + rg] = sm[rg];
    __syncthreads();
    float mean[4];
#pragma unroll
    for (int rg = 0; rg < 4; ++rg) {
        const int row = lg * 4 + rg;
        mean[rg] = (red[0][row] + red[1][row] + red[2][row] + red[3][row]) * (1.f / 256.f);
    }
    __syncthreads();

#pragma unroll
    for (int rg = 0; rg < 4; ++rg) {
        float s2 = 0.f;
#pragma unroll
        for (int j = 0; j < 4; ++j) {
            const float c = acc[j][rg] - mean[rg];
            s2 += c * c;
        }
#pragma unroll
        for (int o = 1; o < 16; o <<= 1) s2 += __shfl_xor(s2, o);
        sm[rg] = s2;
    }
    if (lr == 0)
#pragma unroll
        for (int rg = 0; rg < 4; ++rg) red[wv][lg * 4 + rg] = sm[rg];
    __syncthreads();
    float rstd[4];
#pragma unroll
    for (int rg = 0; rg < 4; ++rg) {
        const int row = lg * 4 + rg;
        const float var = (red[0][row] + red[1][row] + red[2][row] + red[3][row]) * (1.f / 256.f);
        rstd[rg] = rsqrtf(var + 1e-5f);
    }
#pragma unroll
    for (int j = 0; j < 4; ++j) {
        const int col = c0 + j * 16 + lr;
        const float gg = gamma[col], bv = beta[col];
#pragma unroll
        for (int rg = 0; rg < 4; ++rg)
            acc[j][rg] = (acc[j][rg] - mean[rg]) * rstd[rg] * gg + bv;
    }
}

// ---------------------------------------------------------------------------
// oprojqkv: 192 blocks. p6 = bid>>5: prob = p6>>1, ch = p6&1.
// Phase 1 (replicated): oproj+resid(xa)+LN -> xpan (+ xb f32 if p6==0).
// Phase 2: qkv problem prob, col-half ch (L1).
// ---------------------------------------------------------------------------
__global__ __launch_bounds__(256) void oprojqkv(
    const ushort* __restrict__ ao16, const ushort* __restrict__ WoT,
    const float* __restrict__ bo, const float* __restrict__ gamma,
    const float* __restrict__ beta,
    const ushort* __restrict__ WqT, const float* __restrict__ bq,
    const ushort* __restrict__ WkT, const float* __restrict__ bk,
    const ushort* __restrict__ WvT, const float* __restrict__ bv,
    const float* __restrict__ xa, float* __restrict__ xb,
    ushort* __restrict__ q16, ushort* __restrict__ k16,
    ushort* __restrict__ vT16)
{
    __shared__ __align__(16) ushort xpan[16 * XPS];
    __shared__ float red[4][16];
    const int bid  = blockIdx.x;
    const int p6   = bid >> 5;
    const int slab = (bid & 31) * 16;
    const int t = threadIdx.x;
    const int wv = t >> 6, lane = t & 63;
    const int lr = lane & 15, lg = lane >> 4, lk = lg * 8;
    const int c0 = wv * 64;

    f32x4 acc[4];
    oprojln_phase(ao16, WoT, bo, gamma, beta, xa, slab, c0, wv, lr, lg, lk, red, acc);
#pragma unroll
    for (int j = 0; j < 4; ++j) {
        const int col = c0 + j * 16 + lr;
#pragma unroll
        for (int rg = 0; rg < 4; ++rg) {
            if (p6 == 0) xb[(slab + lg * 4 + rg) * HDIM + col] = acc[j][rg];
            xpan[(lg * 4 + rg) * XPS + col] = f2bf(acc[j][rg]);
        }
    }
    __syncthreads();
    const int prob = p6 >> 1, ch = p6 & 1;
    const ushort* Wt = (prob == 0) ? WqT : (prob == 1) ? WkT : WvT;
    const float*  bb = (prob == 0) ? bq  : (prob == 1) ? bk  : bv;
    qkv_one2(xpan, Wt, bb, prob, slab, ch * 128 + wv * 32, lr, lg, lk,
             q16, k16, vT16);
}

// ---------------------------------------------------------------------------
// oprojmlpU: 128 blocks. p4 = bid>>5: p = p4>>1 (mlp/U problem), ch = p4&1.
// Phase 1 (replicated x4): oproj+resid(xb)+LN -> xpan. Phase 2 (x2 per p):
// full o_p panel. Phase 3: U_p col-half ch.
// ---------------------------------------------------------------------------
__global__ __launch_bounds__(256) void oprojmlpU(
    const ushort* __restrict__ ao16, const ushort* __restrict__ WoT,
    const float* __restrict__ bo, const float* __restrict__ gamma,
    const float* __restrict__ beta,
    const ushort* __restrict__ m1WT, const float* __restrict__ m1b,
    const ushort* __restrict__ m2WT, const float* __restrict__ m2b,
    const ushort* __restrict__ cW1aT, const float* __restrict__ cb1,
    const ushort* __restrict__ cW1bT,
    const float* __restrict__ xb, float* __restrict__ U1, float* __restrict__ U2)
{
    __shared__ __align__(16) ushort xpan[16 * XPS];
    __shared__ __align__(16) ushort opan[16 * XPS];
    __shared__ float red[4][16];
    const int bid  = blockIdx.x;
    const int p4   = bid >> 5;
    const int p    = p4 >> 1, ch = p4 & 1;
    const int slab = (bid & 31) * 16;
    const int t = threadIdx.x;
    const int wv = t >> 6, lane = t & 63;
    const int lr = lane & 15, lg = lane >> 4, lk = lg * 8;
    const int c0 = wv * 64;

    f32x4 acc[4];
    oprojln_phase(ao16, WoT, bo, gamma, beta, xb, slab, c0, wv, lr, lg, lk, red, acc);
#pragma unroll
    for (int j = 0; j < 4; ++j) {
        const int col = c0 + j * 16 + lr;
#pragma unroll
        for (int rg = 0; rg < 4; ++rg)
            xpan[(lg * 4 + rg) * XPS + col] = f2bf(acc[j][rg]);
    }
    __syncthreads();

    {   // phase 2: full o_p panel
        const ushort* Wt = p ? m2WT : m1WT;
        const float*  bb = p ? m2b  : m1b;
        const ushort* Ap = xpan + lr * XPS + lk;
        f32x4 a2[4];
#pragma unroll
        for (int j = 0; j < 4; ++j) a2[j] = (f32x4){0.f, 0.f, 0.f, 0.f};
#pragma unroll
        for (int ks = 0; ks < 8; ++ks) {
            const bf16x8 a = *(const bf16x8*)&Ap[ks * 32];
#pragma unroll
            for (int j = 0; j < 4; ++j) {
                const bf16x8 b = *(const bf16x8*)&Wt[(c0 + j * 16 + lr) * HDIM + ks * 32 + lk];
                a2[j] = __builtin_amdgcn_mfma_f32_16x16x32_bf16(a, b, a2[j], 0, 0, 0);
            }
        }
#pragma unroll
        for (int j = 0; j < 4; ++j) {
            const int col = c0 + j * 16 + lr;
            const float bbv = bb[col];
#pragma unroll
            for (int rg = 0; rg < 4; ++rg)
                opan[(lg * 4 + rg) * XPS + col] = f2bf(fmaxf(a2[j][rg] + bbv, 0.f));
        }
    }
    __syncthreads();

    {   // phase 3: U_p, col-half ch (wave = 2 col-groups)
        const ushort* Wt = p ? cW1bT : cW1aT;
        float* U         = p ? U2 : U1;
        const int cb     = ch * 128 + wv * 32;
        const ushort* Ao = opan + lr * XPS + lk;
        f32x4 a2[2];
        a2[0] = (f32x4){0.f, 0.f, 0.f, 0.f};
        a2[1] = (f32x4){0.f, 0.f, 0.f, 0.f};
#pragma unroll
        for (int ks = 0; ks < 8; ++ks) {
            const bf16x8 a = *(const bf16x8*)&Ao[ks * 32];
#pragma unroll
            for (int j = 0; j < 2; ++j) {
                const bf16x8 b = *(const bf16x8*)&Wt[(cb + j * 16 + lr) * HDIM + ks * 32 + lk];
                a2[j] = __builtin_amdgcn_mfma_f32_16x16x32_bf16(a, b, a2[j], 0, 0, 0);
            }
        }
#pragma unroll
        for (int j = 0; j < 2; ++j) {
            const int col = cb + j * 16 + lr;
            const float bbv = (p == 0) ? cb1[col] : 0.f;
#pragma unroll
            for (int rg = 0; rg < 4; ++rg)
                U[(slab + lg * 4 + rg) * HDIM + col] = a2[j][rg] + bbv;
        }
    }
}

// ---------------------------------------------------------------------------
// pair_cls: 32x32 tile, 2x2 per thread, TL copies. (proven)
// ---------------------------------------------------------------------------
__global__ __launch_bounds__(256) void pair_cls(const float* __restrict__ U1,
                                                const float* __restrict__ U2,
                                                const float* __restrict__ W2,
                                                const float* __restrict__ b2,
                                                float* __restrict__ out)
{
    __shared__ __align__(16) float u1s[32][260];
    __shared__ __align__(16) float u2s[32][260];
    __shared__ __align__(16) float w2s[256];
    const int t  = threadIdx.x;
    const int n0 = blockIdx.y * 32, m0 = blockIdx.x * 32;

    for (int i = t; i < 32 * 64; i += 256) {
        const int r = i >> 6, c4 = i & 63;
        *(float4*)&u1s[r][c4 * 4] = *(const float4*)&U1[(n0 + r) * HDIM + c4 * 4];
        *(float4*)&u2s[r][c4 * 4] = *(const float4*)&U2[(m0 + r) * HDIM + c4 * 4];
    }
    if (t < 64) *(float4*)&w2s[t * 4] = *(const float4*)&W2[t * 4];
    __syncthreads();

    const int tx = t & 15, ty = t >> 4;
    float acc[2][2] = {};
    for (int h4 = 0; h4 < 64; ++h4) {
        const float4 a0 = *(const float4*)&u1s[ty * 2][h4 * 4];
        const float4 a1 = *(const float4*)&u1s[ty * 2 + 1][h4 * 4];
        const float4 b0 = *(const float4*)&u2s[tx * 2][h4 * 4];
        const float4 b1 = *(const float4*)&u2s[tx * 2 + 1][h4 * 4];
        const float4 w  = *(const float4*)&w2s[h4 * 4];
#define RT(A, B) fmaxf((A) + (B), 0.f)
        acc[0][0] += RT(a0.x,b0.x)*w.x + RT(a0.y,b0.y)*w.y + RT(a0.z,b0.z)*w.z + RT(a0.w,b0.w)*w.w;
        acc[0][1] += RT(a0.x,b1.x)*w.x + RT(a0.y,b1.y)*w.y + RT(a0.z,b1.z)*w.z + RT(a0.w,b1.w)*w.w;
        acc[1][0] += RT(a1.x,b0.x)*w.x + RT(a1.y,b0.y)*w.y + RT(a1.z,b0.z)*w.z + RT(a1.w,b0.w)*w.w;
        acc[1][1] += RT(a1.x,b1.x)*w.x + RT(a1.y,b1.y)*w.y + RT(a1.z,b1.z)*w.z + RT(a1.w,b1.w)*w.w;
#undef RT
    }
    const float bbv = b2[0];
#pragma unroll
    for (int ii = 0; ii < 2; ++ii)
#pragma unroll
        for (int jj = 0; jj < 2; ++jj) {
            const float val = acc[ii][jj] + bbv;
            const int n = n0 + ty * 2 + ii;
            const int m = m0 + tx * 2 + jj;
#pragma unroll
            for (int tl = 0; tl < TLEN; ++tl)
                out[tl * NTOK * NTOK + n * NTOK + m] = val;
        }
}

// ---------------------------------------------------------------------------
extern "C" void kernel_launch(void* const* d_in, const int* in_sizes, int n_in,
                              void* d_out, int out_size, void* d_ws, size_t ws_size,
                              hipStream_t stream)
{
    const float* hs   = (const float*)d_in[0];
    const float* qf   = hs + 5 * NTOK * HDIM;
    const float* alp  = (const float*)d_in[1];
    const float* pl   = alp + 5 * NTOK * 33;
    const float* fc_W = (const float*)d_in[2];
    const float* fc_b = (const float*)d_in[3];
    const float* Wq   = (const float*)d_in[4];
    const float* bq   = (const float*)d_in[5];
    const float* Wk   = (const float*)d_in[6];
    const float* bk   = (const float*)d_in[7];
    const float* Wv   = (const float*)d_in[8];
    const float* bv   = (const float*)d_in[9];
    const float* Wo   = (const float*)d_in[10];
    const float* bo   = (const float*)d_in[11];
    const float* lng  = (const float*)d_in[12];
    const float* lnb  = (const float*)d_in[13];
    const float* m1W  = (const float*)d_in[14];
    const float* m1b  = (const float*)d_in[15];
    const float* m2W  = (const float*)d_in[16];
    const float* m2b  = (const float*)d_in[17];
    const float* cW1  = (const float*)d_in[18];
    const float* cb1  = (const float*)d_in[19];
    const float* cW2  = (const float*)d_in[20];
    const float* cb2  = (const float*)d_in[21];
    float* out = (float*)d_out;

    const int NN  = NTOK * NTOK;
    const int NH_ = NTOK * HDIM;
    float* ws     = (float*)d_ws;
    float* dist   = ws;                       // NN
    float* dwraw  = ws + NN;                  // NN
    float* inv_cs = ws + 2 * NN;              // 512
    float* xa     = ws + 2 * NN + 512;        // NH
    float* xb     = xa + NH_;                 // NH
    float* U1     = xb + NH_;                 // NH
    float* U2     = U1 + NH_;                 // NH
    ushort* u16   = (ushort*)(U2 + NH_);
    ushort* wpk   = u16;                      // 13 * WSZ
    ushort* q16   = wpk + 13 * WSZ;           // NH
    ushort* k16   = q16 + NH_;                // NH
    ushort* vT16  = k16 + NH_;                // NH ([d][m])
    ushort* ao16  = vT16 + NH_;               // NH

    PKArg pk;
    pk.w[0]  = fc_W;
    pk.w[1]  = Wq;  pk.w[2]  = Wq + WSZ;
    pk.w[3]  = Wk;  pk.w[4]  = Wk + WSZ;
    pk.w[5]  = Wv;  pk.w[6]  = Wv + WSZ;
    pk.w[7]  = Wo;  pk.w[8]  = Wo + WSZ;
    pk.w[9]  = m1W; pk.w[10] = m2W;
    pk.w[11] = cW1; pk.w[12] = cW1 + WSZ;
    pk.pl = pl;
    pk.wpk = wpk;
    pk.dist = dist; pk.dwraw = dwraw; pk.inv_cs = inv_cs;
    pack_kernel<<<216, 256, 0, stream>>>(pk);

    // fc (replicated x6) + qkv (L0)
    fcqkv<<<192, 256, 0, stream>>>(
        qf, wpk + 0 * WSZ, fc_b,
        wpk + 1 * WSZ, bq, wpk + 3 * WSZ, bk, wpk + 5 * WSZ, bv,
        xa, q16, k16, vT16);

    attn_fused<<<128, 512, 0, stream>>>(q16, k16, vT16, dist, dwraw, inv_cs, ao16);

    // oproj+LN (L0, replicated x6) -> qkv (L1)
    oprojqkv<<<192, 256, 0, stream>>>(
        ao16, wpk + 7 * WSZ, bo, lng, lnb,
        wpk + 2 * WSZ, bq + HDIM, wpk + 4 * WSZ, bk + HDIM,
        wpk + 6 * WSZ, bv + HDIM,
        xa, xb, q16, k16, vT16);

    attn_fused<<<128, 512, 0, stream>>>(q16, k16, vT16, dist, dwraw, inv_cs, ao16);

    // oproj+LN (L1, replicated x4) -> mlp_p -> U_p (col-halves)
    oprojmlpU<<<128, 256, 0, stream>>>(
        ao16, wpk + 8 * WSZ, bo + HDIM, lng + HDIM, lnb + HDIM,
        wpk + 9 * WSZ, m1b, wpk + 10 * WSZ, m2b,
        wpk + 11 * WSZ, cb1, wpk + 12 * WSZ,
        xb, U1, U2);

    pair_cls<<<dim3(16, 16), 256, 0, stream>>>(U1, U2, cW2, cb2, out);
}

// Round 14
// 95.657 us; speedup vs baseline: 1.6019x; 1.0213x over previous
//
#include <hip/hip_runtime.h>
#include <math.h>

// ---------------------------------------------------------------------------
// SpatialProximityHead on MI355X — round 13: r12 + pair_cls bf16-LDS +
// attn PV (d-block, key-half) wave split. 7 dispatches.
// pack(216) -> fcqkv(192) -> attn(128x512) -> oprojqkv(192) -> attn
//           -> oprojmlpU(128) -> pair(256)
// ---------------------------------------------------------------------------

#define NTOK 512
#define HDIM 256
#define DKH  64
#define NHEAD 4
#define TLEN 6
#define WSZ  65536
#define PSTR 520   // attn P_lds ushort stride
#define XPS  264   // LDS panel ushort stride

typedef __attribute__((ext_vector_type(8))) short bf16x8;
typedef __attribute__((ext_vector_type(4))) float f32x4;

__device__ __forceinline__ ushort f2bf(float f)
{
    unsigned u = __builtin_bit_cast(unsigned, f);
    u += 0x7FFFu + ((u >> 16) & 1u);     // RNE
    return (ushort)(u >> 16);
}
__device__ __forceinline__ float bf_lo(unsigned u)
{
    return __builtin_bit_cast(float, u << 16);
}
__device__ __forceinline__ float bf_hi(unsigned u)
{
    return __builtin_bit_cast(float, u & 0xFFFF0000u);
}

struct PKArg {
    const float* w[13];
    const float* pl;
    ushort* wpk;
    float *dist, *dwraw, *inv_cs;
};

// ---------------------------------------------------------------------------
// pack: 0-207 weight 64x64 transpose tiles ([col][k] bf16); 208-215 dist prep.
// ---------------------------------------------------------------------------
__global__ __launch_bounds__(256) void pack_kernel(PKArg p)
{
    __shared__ __align__(16) ushort smu[64 * 72];
    const int bid = blockIdx.x;
    const int t   = threadIdx.x;

    if (bid < 208) {
        const int mat  = bid >> 4;
        const int tile = bid & 15;
        const int k0   = (tile >> 2) * 64;
        const int c0   = (tile & 3) * 64;
        const float* W = p.w[mat];
#pragma unroll
        for (int j = 0; j < 4; ++j) {
            const int i  = t + j * 256;
            const int r  = i >> 4, c4 = i & 15;
            const float4 v4 = *(const float4*)&W[(k0 + r) * HDIM + c0 + c4 * 4];
            smu[(c4 * 4 + 0) * 72 + r] = f2bf(v4.x);
            smu[(c4 * 4 + 1) * 72 + r] = f2bf(v4.y);
            smu[(c4 * 4 + 2) * 72 + r] = f2bf(v4.z);
            smu[(c4 * 4 + 3) * 72 + r] = f2bf(v4.w);
        }
        __syncthreads();
#pragma unroll
        for (int j = 0; j < 2; ++j) {
            const int i  = t + j * 256;
            const int cr = i >> 3, kk = i & 7;
            const uint4 v = *(const uint4*)&smu[cr * 72 + kk * 8];
            *(uint4*)&p.wpk[mat * WSZ + (c0 + cr) * HDIM + k0 + kk * 8] = v;
        }
    } else {
        float* smf = (float*)smu;
        float* qe  = smf;            // [512][3]
        float* red = smf + 1536;     // [4][64]
        const int item = bid - 208;
        for (int i = t; i < 512; i += 256) {
            qe[i * 3 + 0] = p.pl[i * 33 + 30];
            qe[i * 3 + 1] = p.pl[i * 33 + 31];
            qe[i * 3 + 2] = p.pl[i * 33 + 32];
        }
        __syncthreads();
        const int m   = item * 64 + (t & 63);
        const int nch = t >> 6;
        const float kx = p.pl[m * 33 + 0], ky = p.pl[m * 33 + 1], kz = p.pl[m * 33 + 2];
        float cs = 0.f;
        for (int n = nch * 128; n < nch * 128 + 128; ++n) {
            const float dx = kx - qe[n * 3 + 0];
            const float dy = ky - qe[n * 3 + 1];
            const float dz = kz - qe[n * 3 + 2];
            const float dd = sqrtf(dx * dx + dy * dy + dz * dz);
            const float w  = 1.0f / (dd + 0.01f);
            p.dist[n * NTOK + m]  = dd;
            p.dwraw[n * NTOK + m] = w;
            cs += w;
        }
        red[nch * 64 + (t & 63)] = cs;
        __syncthreads();
        if (t < 64)
            p.inv_cs[item * 64 + t] =
                1.0f / (red[t] + red[64 + t] + red[128 + t] + red[192 + t]);
    }
}

// ---------------------------------------------------------------------------
// qkv_one2: one qkv problem, 2 col-groups starting at c0. prob: 0->q16,
// 1->k16 (row-major), 2->vT16 (transposed).
// ---------------------------------------------------------------------------
__device__ __forceinline__ void qkv_one2(
    const ushort* __restrict__ xpan, const ushort* __restrict__ Wt,
    const float* __restrict__ bb, int prob,
    int slab, int c0, int lr, int lg, int lk,
    ushort* __restrict__ q16, ushort* __restrict__ k16,
    ushort* __restrict__ vT16)
{
    const ushort* Ap = xpan + lr * XPS + lk;
    f32x4 acc[2];
    acc[0] = (f32x4){0.f, 0.f, 0.f, 0.f};
    acc[1] = (f32x4){0.f, 0.f, 0.f, 0.f};
#pragma unroll
    for (int ks = 0; ks < 8; ++ks) {
        const bf16x8 a = *(const bf16x8*)&Ap[ks * 32];
#pragma unroll
        for (int j = 0; j < 2; ++j) {
            const bf16x8 b = *(const bf16x8*)&Wt[(c0 + j * 16 + lr) * HDIM + ks * 32 + lk];
            acc[j] = __builtin_amdgcn_mfma_f32_16x16x32_bf16(a, b, acc[j], 0, 0, 0);
        }
    }
#pragma unroll
    for (int j = 0; j < 2; ++j) {
        const int col = c0 + j * 16 + lr;
        const float bv2 = bb[col];
        if (prob < 2) {
            ushort* dst = (prob == 0) ? q16 : k16;
#pragma unroll
            for (int rg = 0; rg < 4; ++rg)
                dst[(slab + lg * 4 + rg) * HDIM + col] = f2bf(acc[j][rg] + bv2);
        } else {
            ushort4 s = {f2bf(acc[j][0] + bv2), f2bf(acc[j][1] + bv2),
                         f2bf(acc[j][2] + bv2), f2bf(acc[j][3] + bv2)};
            *(ushort4*)&vT16[col * NTOK + slab + lg * 4] = s;
        }
    }
}

// ---------------------------------------------------------------------------
// fcqkv: 192 blocks. p6 = bid>>5 (0..5): prob = p6>>1, ch = p6&1.
// ---------------------------------------------------------------------------
__global__ __launch_bounds__(256) void fcqkv(
    const float* __restrict__ qf, const ushort* __restrict__ fcWt,
    const float* __restrict__ fcb,
    const ushort* __restrict__ WqT, const float* __restrict__ bq,
    const ushort* __restrict__ WkT, const float* __restrict__ bk,
    const ushort* __restrict__ WvT, const float* __restrict__ bv,
    float* __restrict__ xa, ushort* __restrict__ q16,
    ushort* __restrict__ k16, ushort* __restrict__ vT16)
{
    __shared__ __align__(16) ushort xpan[16 * XPS];
    const int bid  = blockIdx.x;
    const int p6   = bid >> 5;
    const int slab = (bid & 31) * 16;
    const int t = threadIdx.x;
    const int wv = t >> 6, lane = t & 63;
    const int lr = lane & 15, lg = lane >> 4, lk = lg * 8;
    const int c0 = wv * 64;

    {   // phase 1: fc (replicated)
        f32x4 acc[4];
#pragma unroll
        for (int j = 0; j < 4; ++j) acc[j] = (f32x4){0.f, 0.f, 0.f, 0.f};
        const float* Aq = qf + (slab + lr) * HDIM + lk;
#pragma unroll
        for (int ks = 0; ks < 8; ++ks) {
            const float4 a0 = *(const float4*)&Aq[ks * 32];
            const float4 a1 = *(const float4*)&Aq[ks * 32 + 4];
            bf16x8 a;
            a[0] = (short)f2bf(a0.x); a[1] = (short)f2bf(a0.y);
            a[2] = (short)f2bf(a0.z); a[3] = (short)f2bf(a0.w);
            a[4] = (short)f2bf(a1.x); a[5] = (short)f2bf(a1.y);
            a[6] = (short)f2bf(a1.z); a[7] = (short)f2bf(a1.w);
#pragma unroll
            for (int j = 0; j < 4; ++j) {
                const bf16x8 b = *(const bf16x8*)&fcWt[(c0 + j * 16 + lr) * HDIM + ks * 32 + lk];
                acc[j] = __builtin_amdgcn_mfma_f32_16x16x32_bf16(a, b, acc[j], 0, 0, 0);
            }
        }
#pragma unroll
        for (int j = 0; j < 4; ++j) {
            const int col = c0 + j * 16 + lr;
            const float bbv = fcb[col];
#pragma unroll
            for (int rg = 0; rg < 4; ++rg) {
                const float o = fmaxf(acc[j][rg] + bbv, 0.f);
                if (p6 == 0) xa[(slab + lg * 4 + rg) * HDIM + col] = o;
                xpan[(lg * 4 + rg) * XPS + col] = f2bf(o);
            }
        }
    }
    __syncthreads();
    const int prob = p6 >> 1, ch = p6 & 1;
    const ushort* Wt = (prob == 0) ? WqT : (prob == 1) ? WkT : WvT;
    const float*  bb = (prob == 0) ? bq  : (prob == 1) ? bk  : bv;
    qkv_one2(xpan, Wt, bb, prob, slab, ch * 128 + wv * 32, lr, lg, lk,
             q16, k16, vT16);
}

// ---------------------------------------------------------------------------
// attn_fused: 128 blocks x 512 thr. QK^T wave = key-slice of 64 (as r12);
// PV wave = (d-block = wv&3, key-half = wv>>2) -> exch only 2-way.
// ---------------------------------------------------------------------------
__global__ __launch_bounds__(512) void attn_fused(
    const ushort* __restrict__ q16, const ushort* __restrict__ k16,
    const ushort* __restrict__ vT16, const float* __restrict__ dist,
    const float* __restrict__ dwraw, const float* __restrict__ inv_cs,
    ushort* __restrict__ ao16)
{
    __shared__ __align__(16) ushort P_lds[16 * PSTR];   // 16.6 KB
    __shared__ __align__(16) float exch[2][16][64];     // 8 KB
    __shared__ float rmax[8][16];
    __shared__ float psums[8][16];

    const int bid = blockIdx.x;
    const int h  = bid >> 5;
    const int n0 = (bid & 31) * 16;
    const int t  = threadIdx.x;
    const int wv = t >> 6, lane = t & 63;
    const int lr = lane & 15, lg = lane >> 4, lk = lg * 8;
    const int mW = wv * 64;

    const ushort* Qrow = q16 + (n0 + lr) * HDIM + h * DKH + lk;
    const bf16x8 a0 = *(const bf16x8*)&Qrow[0];
    const bf16x8 a1 = *(const bf16x8*)&Qrow[32];

    // ---- S = Q @ K^T (16 x 64 per wave) ----
    f32x4 accs[4];
#pragma unroll
    for (int cg = 0; cg < 4; ++cg) accs[cg] = (f32x4){0.f, 0.f, 0.f, 0.f};
#pragma unroll
    for (int cg = 0; cg < 4; ++cg) {
        const ushort* Brow = k16 + (mW + cg * 16 + lr) * HDIM + h * DKH + lk;
        accs[cg] = __builtin_amdgcn_mfma_f32_16x16x32_bf16(
            a0, *(const bf16x8*)&Brow[0], accs[cg], 0, 0, 0);
        accs[cg] = __builtin_amdgcn_mfma_f32_16x16x32_bf16(
            a1, *(const bf16x8*)&Brow[32], accs[cg], 0, 0, 0);
    }

    // ---- scale + bias ----
    float s[4][4];
#pragma unroll
    for (int cg = 0; cg < 4; ++cg) {
        const int m = mW + cg * 16 + lr;
        const float ic = (h == 0) ? inv_cs[m] : 0.f;
#pragma unroll
        for (int rg = 0; rg < 4; ++rg) {
            const int n = n0 + lg * 4 + rg;
            float b = 0.f;
            if (h == 0)      b = dwraw[n * NTOK + m] * ic;
            else if (h == 1) b = -dist[n * NTOK + m];
            s[cg][rg] = accs[cg][rg] * 0.125f + b;
        }
    }

    // ---- row max ----
    float mx[4];
#pragma unroll
    for (int rg = 0; rg < 4; ++rg) {
        float m = fmaxf(fmaxf(s[0][rg], s[1][rg]), fmaxf(s[2][rg], s[3][rg]));
#pragma unroll
        for (int o = 1; o < 16; o <<= 1) m = fmaxf(m, __shfl_xor(m, o));
        mx[rg] = m;
    }
    if (lr == 0)
#pragma unroll
        for (int rg = 0; rg < 4; ++rg) rmax[wv][lg * 4 + rg] = mx[rg];
    __syncthreads();
    float mxf[4];
#pragma unroll
    for (int rg = 0; rg < 4; ++rg) {
        const int row = lg * 4 + rg;
        float m = rmax[0][row];
#pragma unroll
        for (int w = 1; w < 8; ++w) m = fmaxf(m, rmax[w][row]);
        mxf[rg] = m;
    }

    // ---- exp, partial sums, P -> LDS (bf16) ----
    float ps[4] = {0.f, 0.f, 0.f, 0.f};
#pragma unroll
    for (int cg = 0; cg < 4; ++cg)
#pragma unroll
        for (int rg = 0; rg < 4; ++rg) {
            const float e = __expf(s[cg][rg] - mxf[rg]);
            ps[rg] += e;
            P_lds[(lg * 4 + rg) * PSTR + mW + cg * 16 + lr] = f2bf(e);
        }
#pragma unroll
    for (int rg = 0; rg < 4; ++rg) {
#pragma unroll
        for (int o = 1; o < 16; o <<= 1) ps[rg] += __shfl_xor(ps[rg], o);
    }
    if (lr == 0)
#pragma unroll
        for (int rg = 0; rg < 4; ++rg) psums[wv][lg * 4 + rg] = ps[rg];
    __syncthreads();

    // ---- PV: wave = (db = wv&3, kh = wv>>2), 256 keys each ----
    {
        const int db = wv & 3, kh = wv >> 2;
        f32x4 acco = (f32x4){0.f, 0.f, 0.f, 0.f};
        const ushort* Vrow = vT16 + (h * DKH + db * 16 + lr) * NTOK + kh * 256 + lk;
        const ushort* Prow = P_lds + lr * PSTR + kh * 256 + lk;
#pragma unroll
        for (int c = 0; c < 8; ++c) {
            const bf16x8 pa = *(const bf16x8*)&Prow[c * 32];
            const bf16x8 b  = *(const bf16x8*)&Vrow[c * 32];
            acco = __builtin_amdgcn_mfma_f32_16x16x32_bf16(pa, b, acco, 0, 0, 0);
        }
#pragma unroll
        for (int rg = 0; rg < 4; ++rg)
            exch[kh][lg * 4 + rg][db * 16 + lr] = acco[rg];
    }
    __syncthreads();

    // ---- combine 2 partials + 1/rowsum + store (threads 0..255) ----
    if (t < 256) {
        const int r = t >> 4, d4 = t & 15;
        f32x4 sum = *(const f32x4*)&exch[0][r][d4 * 4];
        sum += *(const f32x4*)&exch[1][r][d4 * 4];
        float den = 0.f;
#pragma unroll
        for (int w = 0; w < 8; ++w) den += psums[w][r];
        const float inv = 1.0f / den;
        ushort4 o = {f2bf(sum.x * inv), f2bf(sum.y * inv),
                     f2bf(sum.z * inv), f2bf(sum.w * inv)};
        *(ushort4*)&ao16[(n0 + r) * HDIM + h * DKH + d4 * 4] = o;
    }
}

// ---------------------------------------------------------------------------
// oproj+LN phase (proven): normalized values left in acc.
// ---------------------------------------------------------------------------
__device__ __forceinline__ void oprojln_phase(
    const ushort* __restrict__ ao16, const ushort* __restrict__ WoT,
    const float* __restrict__ bo, const float* __restrict__ gamma,
    const float* __restrict__ beta, const float* __restrict__ x,
    int slab, int c0, int wv, int lr, int lg, int lk,
    float red[4][16], f32x4 acc[4])
{
    const ushort* Arow = ao16 + (slab + lr) * HDIM + lk;
#pragma unroll
    for (int j = 0; j < 4; ++j) acc[j] = (f32x4){0.f, 0.f, 0.f, 0.f};
#pragma unroll
    for (int ks = 0; ks < 8; ++ks) {
        const bf16x8 a = *(const bf16x8*)&Arow[ks * 32];
#pragma unroll
        for (int j = 0; j < 4; ++j) {
            const bf16x8 b = *(const bf16x8*)&WoT[(c0 + j * 16 + lr) * HDIM + ks * 32 + lk];
            acc[j] = __builtin_amdgcn_mfma_f32_16x16x32_bf16(a, b, acc[j], 0, 0, 0);
        }
    }
#pragma unroll
    for (int j = 0; j < 4; ++j) {
        const int col = c0 + j * 16 + lr;
        const float bc = bo[col];
#pragma unroll
        for (int rg = 0; rg < 4; ++rg)
            acc[j][rg] += bc + x[(slab + lg * 4 + rg) * HDIM + col];
    }

    float sm[4];
#pragma unroll
    for (int rg = 0; rg < 4; ++rg) {
        float s = 0.f;
#pragma unroll
        for (int j = 0; j < 4; ++j) s += acc[j][rg];
#pragma unroll
        for (int o = 1; o < 16; o <<= 1) s += __shfl_xor(s, o);
        sm[rg] = s;
    }
    if (lr == 0)
#pragma unroll
        for (int rg = 0; rg < 4; ++rg) red[wv][lg * 4 + rg] = sm[rg];
    __syncthreads();
    float mean[4];
#pragma unroll
    for (int rg = 0; rg < 4; ++rg) {
        const int row = lg * 4 + rg;
        mean[rg] = (red[0][row] + red[1][row] + red[2][row] + red[3][row]) * (1.f / 256.f);
    }
    __syncthreads();

#pragma unroll
    for (int rg = 0; rg < 4; ++rg) {
        float s2 = 0.f;
#pragma unroll
        for (int j = 0; j < 4; ++j) {
            const float c = acc[j][rg] - mean[rg];
            s2 += c * c;
        }
#pragma unroll
        for (int o = 1; o < 16; o <<= 1) s2 += __shfl_xor(s2, o);
        sm[rg] = s2;
    }
    if (lr == 0)
#pragma unroll
        for (int rg = 0; rg < 4; ++rg) red[wv][lg * 4 + rg] = sm[rg];
    __syncthreads();
    float rstd[4];
#pragma unroll
    for (int rg = 0; rg < 4; ++rg) {
        const int row = lg * 4 + rg;
        const float var = (red[0][row] + red[1][row] + red[2][row] + red[3][row]) * (1.f / 256.f);
        rstd[rg] = rsqrtf(var + 1e-5f);
    }
#pragma unroll
    for (int j = 0; j < 4; ++j) {
        const int col = c0 + j * 16 + lr;
        const float gg = gamma[col], bv = beta[col];
#pragma unroll
        for (int rg = 0; rg < 4; ++rg)
            acc[j][rg] = (acc[j][rg] - mean[rg]) * rstd[rg] * gg + bv;
    }
}

// ---------------------------------------------------------------------------
// oprojqkv: 192 blocks. p6 = bid>>5: prob = p6>>1, ch = p6&1.
// ---------------------------------------------------------------------------
__global__ __launch_bounds__(256) void oprojqkv(
    const ushort* __restrict__ ao16, const ushort* __restrict__ WoT,
    const float* __restrict__ bo, const float* __restrict__ gamma,
    const float* __restrict__ beta,
    const ushort* __restrict__ WqT, const float* __restrict__ bq,
    const ushort* __restrict__ WkT, const float* __restrict__ bk,
    const ushort* __restrict__ WvT, const float* __restrict__ bv,
    const float* __restrict__ xa, float* __restrict__ xb,
    ushort* __restrict__ q16, ushort* __restrict__ k16,
    ushort* __restrict__ vT16)
{
    __shared__ __align__(16) ushort xpan[16 * XPS];
    __shared__ float red[4][16];
    const int bid  = blockIdx.x;
    const int p6   = bid >> 5;
    const int slab = (bid & 31) * 16;
    const int t = threadIdx.x;
    const int wv = t >> 6, lane = t & 63;
    const int lr = lane & 15, lg = lane >> 4, lk = lg * 8;
    const int c0 = wv * 64;

    f32x4 acc[4];
    oprojln_phase(ao16, WoT, bo, gamma, beta, xa, slab, c0, wv, lr, lg, lk, red, acc);
#pragma unroll
    for (int j = 0; j < 4; ++j) {
        const int col = c0 + j * 16 + lr;
#pragma unroll
        for (int rg = 0; rg < 4; ++rg) {
            if (p6 == 0) xb[(slab + lg * 4 + rg) * HDIM + col] = acc[j][rg];
            xpan[(lg * 4 + rg) * XPS + col] = f2bf(acc[j][rg]);
        }
    }
    __syncthreads();
    const int prob = p6 >> 1, ch = p6 & 1;
    const ushort* Wt = (prob == 0) ? WqT : (prob == 1) ? WkT : WvT;
    const float*  bb = (prob == 0) ? bq  : (prob == 1) ? bk  : bv;
    qkv_one2(xpan, Wt, bb, prob, slab, ch * 128 + wv * 32, lr, lg, lk,
             q16, k16, vT16);
}

// ---------------------------------------------------------------------------
// oprojmlpU: 128 blocks. p4 = bid>>5: p = p4>>1, ch = p4&1.
// U1/U2 written as bf16.
// ---------------------------------------------------------------------------
__global__ __launch_bounds__(256) void oprojmlpU(
    const ushort* __restrict__ ao16, const ushort* __restrict__ WoT,
    const float* __restrict__ bo, const float* __restrict__ gamma,
    const float* __restrict__ beta,
    const ushort* __restrict__ m1WT, const float* __restrict__ m1b,
    const ushort* __restrict__ m2WT, const float* __restrict__ m2b,
    const ushort* __restrict__ cW1aT, const float* __restrict__ cb1,
    const ushort* __restrict__ cW1bT,
    const float* __restrict__ xb, ushort* __restrict__ U1b,
    ushort* __restrict__ U2b)
{
    __shared__ __align__(16) ushort xpan[16 * XPS];
    __shared__ __align__(16) ushort opan[16 * XPS];
    __shared__ float red[4][16];
    const int bid  = blockIdx.x;
    const int p4   = bid >> 5;
    const int p    = p4 >> 1, ch = p4 & 1;
    const int slab = (bid & 31) * 16;
    const int t = threadIdx.x;
    const int wv = t >> 6, lane = t & 63;
    const int lr = lane & 15, lg = lane >> 4, lk = lg * 8;
    const int c0 = wv * 64;

    f32x4 acc[4];
    oprojln_phase(ao16, WoT, bo, gamma, beta, xb, slab, c0, wv, lr, lg, lk, red, acc);
#pragma unroll
    for (int j = 0; j < 4; ++j) {
        const int col = c0 + j * 16 + lr;
#pragma unroll
        for (int rg = 0; rg < 4; ++rg)
            xpan[(lg * 4 + rg) * XPS + col] = f2bf(acc[j][rg]);
    }
    __syncthreads();

    {   // phase 2: full o_p panel
        const ushort* Wt = p ? m2WT : m1WT;
        const float*  bb = p ? m2b  : m1b;
        const ushort* Ap = xpan + lr * XPS + lk;
        f32x4 a2[4];
#pragma unroll
        for (int j = 0; j < 4; ++j) a2[j] = (f32x4){0.f, 0.f, 0.f, 0.f};
#pragma unroll
        for (int ks = 0; ks < 8; ++ks) {
            const bf16x8 a = *(const bf16x8*)&Ap[ks * 32];
#pragma unroll
            for (int j = 0; j < 4; ++j) {
                const bf16x8 b = *(const bf16x8*)&Wt[(c0 + j * 16 + lr) * HDIM + ks * 32 + lk];
                a2[j] = __builtin_amdgcn_mfma_f32_16x16x32_bf16(a, b, a2[j], 0, 0, 0);
            }
        }
#pragma unroll
        for (int j = 0; j < 4; ++j) {
            const int col = c0 + j * 16 + lr;
            const float bbv = bb[col];
#pragma unroll
            for (int rg = 0; rg < 4; ++rg)
                opan[(lg * 4 + rg) * XPS + col] = f2bf(fmaxf(a2[j][rg] + bbv, 0.f));
        }
    }
    __syncthreads();

    {   // phase 3: U_p, col-half ch (wave = 2 col-groups), bf16 output
        const ushort* Wt = p ? cW1bT : cW1aT;
        ushort* U        = p ? U2b : U1b;
        const int cb     = ch * 128 + wv * 32;
        const ushort* Ao = opan + lr * XPS + lk;
        f32x4 a2[2];
        a2[0] = (f32x4){0.f, 0.f, 0.f, 0.f};
        a2[1] = (f32x4){0.f, 0.f, 0.f, 0.f};
#pragma unroll
        for (int ks = 0; ks < 8; ++ks) {
            const bf16x8 a = *(const bf16x8*)&Ao[ks * 32];
#pragma unroll
            for (int j = 0; j < 2; ++j) {
                const bf16x8 b = *(const bf16x8*)&Wt[(cb + j * 16 + lr) * HDIM + ks * 32 + lk];
                a2[j] = __builtin_amdgcn_mfma_f32_16x16x32_bf16(a, b, a2[j], 0, 0, 0);
            }
        }
#pragma unroll
        for (int j = 0; j < 2; ++j) {
            const int col = cb + j * 16 + lr;
            const float bbv = (p == 0) ? cb1[col] : 0.f;
#pragma unroll
            for (int rg = 0; rg < 4; ++rg)
                U[(slab + lg * 4 + rg) * HDIM + col] = f2bf(a2[j][rg] + bbv);
        }
    }
}

// ---------------------------------------------------------------------------
// pair_cls: 32x32 tile, 2x2/thread. bf16 LDS panels (raw uint4 copies),
// f32 w2, in-loop unpack. 8 h per b128 read.
// ---------------------------------------------------------------------------
__global__ __launch_bounds__(256) void pair_cls(const ushort* __restrict__ U1b,
                                                const ushort* __restrict__ U2b,
                                                const float* __restrict__ W2,
                                                const float* __restrict__ b2,
                                                float* __restrict__ out)
{
    __shared__ __align__(16) ushort u1s[32][264];
    __shared__ __align__(16) ushort u2s[32][264];
    __shared__ __align__(16) float w2s[256];
    const int t  = threadIdx.x;
    const int n0 = blockIdx.y * 32, m0 = blockIdx.x * 32;

#pragma unroll
    for (int u = 0; u < 4; ++u) {
        const int i = t + u * 256;          // 0..1023 = 32 rows x 32 uint4
        const int r = i >> 5, c8 = i & 31;
        *(uint4*)&u1s[r][c8 * 8] = *(const uint4*)&U1b[(n0 + r) * HDIM + c8 * 8];
        *(uint4*)&u2s[r][c8 * 8] = *(const uint4*)&U2b[(m0 + r) * HDIM + c8 * 8];
    }
    if (t < 64) *(float4*)&w2s[t * 4] = *(const float4*)&W2[t * 4];
    __syncthreads();

    const int tx = t & 15, ty = t >> 4;
    const ushort* r0 = &u1s[ty * 2][0];
    const ushort* r1 = &u1s[ty * 2 + 1][0];
    const ushort* c0 = &u2s[tx * 2][0];
    const ushort* c1 = &u2s[tx * 2 + 1][0];
    float acc[2][2] = {};

#define RT(A, B) fmaxf((A) + (B), 0.f)
    for (int h8 = 0; h8 < 32; ++h8) {
        const uint4 A0 = *(const uint4*)&r0[h8 * 8];
        const uint4 A1 = *(const uint4*)&r1[h8 * 8];
        const uint4 B0 = *(const uint4*)&c0[h8 * 8];
        const uint4 B1 = *(const uint4*)&c1[h8 * 8];
        const float4 w0 = *(const float4*)&w2s[h8 * 8];
        const float4 w1 = *(const float4*)&w2s[h8 * 8 + 4];
        const float warr[8] = {w0.x, w0.y, w0.z, w0.w, w1.x, w1.y, w1.z, w1.w};
#pragma unroll
        for (int q = 0; q < 4; ++q) {
            const unsigned a0u = ((const unsigned*)&A0)[q];
            const unsigned a1u = ((const unsigned*)&A1)[q];
            const unsigned b0u = ((const unsigned*)&B0)[q];
            const unsigned b1u = ((const unsigned*)&B1)[q];
            const float a0l = bf_lo(a0u), a0h = bf_hi(a0u);
            const float a1l = bf_lo(a1u), a1h = bf_hi(a1u);
            const float b0l = bf_lo(b0u), b0h = bf_hi(b0u);
            const float b1l = bf_lo(b1u), b1h = bf_hi(b1u);
            const float wl = warr[q * 2], wh = warr[q * 2 + 1];
            acc[0][0] += RT(a0l, b0l) * wl + RT(a0h, b0h) * wh;
            acc[0][1] += RT(a0l, b1l) * wl + RT(a0h, b1h) * wh;
            acc[1][0] += RT(a1l, b0l) * wl + RT(a1h, b0h) * wh;
            acc[1][1] += RT(a1l, b1l) * wl + RT(a1h, b1h) * wh;
        }
    }
#undef RT

    const float bbv = b2[0];
#pragma unroll
    for (int ii = 0; ii < 2; ++ii)
#pragma unroll
        for (int jj = 0; jj < 2; ++jj) {
            const float val = acc[ii][jj] + bbv;
            const int n = n0 + ty * 2 + ii;
            const int m = m0 + tx * 2 + jj;
#pragma unroll
            for (int tl = 0; tl < TLEN; ++tl)
                out[tl * NTOK * NTOK + n * NTOK + m] = val;
        }
}

// ---------------------------------------------------------------------------
extern "C" void kernel_launch(void* const* d_in, const int* in_sizes, int n_in,
                              void* d_out, int out_size, void* d_ws, size_t ws_size,
                              hipStream_t stream)
{
    const float* hs   = (const float*)d_in[0];
    const float* qf   = hs + 5 * NTOK * HDIM;
    const float* alp  = (const float*)d_in[1];
    const float* pl   = alp + 5 * NTOK * 33;
    const float* fc_W = (const float*)d_in[2];
    const float* fc_b = (const float*)d_in[3];
    const float* Wq   = (const float*)d_in[4];
    const float* bq   = (const float*)d_in[5];
    const float* Wk   = (const float*)d_in[6];
    const float* bk   = (const float*)d_in[7];
    const float* Wv   = (const float*)d_in[8];
    const float* bv   = (const float*)d_in[9];
    const float* Wo   = (const float*)d_in[10];
    const float* bo   = (const float*)d_in[11];
    const float* lng  = (const float*)d_in[12];
    const float* lnb  = (const float*)d_in[13];
    const float* m1W  = (const float*)d_in[14];
    const float* m1b  = (const float*)d_in[15];
    const float* m2W  = (const float*)d_in[16];
    const float* m2b  = (const float*)d_in[17];
    const float* cW1  = (const float*)d_in[18];
    const float* cb1  = (const float*)d_in[19];
    const float* cW2  = (const float*)d_in[20];
    const float* cb2  = (const float*)d_in[21];
    float* out = (float*)d_out;

    const int NN  = NTOK * NTOK;
    const int NH_ = NTOK * HDIM;
    float* ws     = (float*)d_ws;
    float* dist   = ws;                       // NN
    float* dwraw  = ws + NN;                  // NN
    float* inv_cs = ws + 2 * NN;              // 512
    float* xa     = ws + 2 * NN + 512;        // NH
    float* xb     = xa + NH_;                 // NH
    ushort* u16   = (ushort*)(xb + NH_);
    ushort* wpk   = u16;                      // 13 * WSZ
    ushort* q16   = wpk + 13 * WSZ;           // NH
    ushort* k16   = q16 + NH_;                // NH
    ushort* vT16  = k16 + NH_;                // NH ([d][m])
    ushort* ao16  = vT16 + NH_;               // NH
    ushort* U1b   = ao16 + NH_;               // NH
    ushort* U2b   = U1b + NH_;                // NH

    PKArg pk;
    pk.w[0]  = fc_W;
    pk.w[1]  = Wq;  pk.w[2]  = Wq + WSZ;
    pk.w[3]  = Wk;  pk.w[4]  = Wk + WSZ;
    pk.w[5]  = Wv;  pk.w[6]  = Wv + WSZ;
    pk.w[7]  = Wo;  pk.w[8]  = Wo + WSZ;
    pk.w[9]  = m1W; pk.w[10] = m2W;
    pk.w[11] = cW1; pk.w[12] = cW1 + WSZ;
    pk.pl = pl;
    pk.wpk = wpk;
    pk.dist = dist; pk.dwraw = dwraw; pk.inv_cs = inv_cs;
    pack_kernel<<<216, 256, 0, stream>>>(pk);

    // fc (replicated x6) + qkv (L0)
    fcqkv<<<192, 256, 0, stream>>>(
        qf, wpk + 0 * WSZ, fc_b,
        wpk + 1 * WSZ, bq, wpk + 3 * WSZ, bk, wpk + 5 * WSZ, bv,
        xa, q16, k16, vT16);

    attn_fused<<<128, 512, 0, stream>>>(q16, k16, vT16, dist, dwraw, inv_cs, ao16);

    // oproj+LN (L0, replicated x6) -> qkv (L1)
    oprojqkv<<<192, 256, 0, stream>>>(
        ao16, wpk + 7 * WSZ, bo, lng, lnb,
        wpk + 2 * WSZ, bq + HDIM, wpk + 4 * WSZ, bk + HDIM,
        wpk + 6 * WSZ, bv + HDIM,
        xa, xb, q16, k16, vT16);

    attn_fused<<<128, 512, 0, stream>>>(q16, k16, vT16, dist, dwraw, inv_cs, ao16);

    // oproj+LN (L1, replicated x4) -> mlp_p -> U_p (bf16 out)
    oprojmlpU<<<128, 256, 0, stream>>>(
        ao16, wpk + 8 * WSZ, bo + HDIM, lng + HDIM, lnb + HDIM,
        wpk + 9 * WSZ, m1b, wpk + 10 * WSZ, m2b,
        wpk + 11 * WSZ, cb1, wpk + 12 * WSZ,
        xb, U1b, U2b);

    pair_cls<<<dim3(16, 16), 256, 0, stream>>>(U1b, U2b, cW2, cb2, out);
}